// Round 3
// baseline (120.843 us; speedup 1.0000x reference)
//
#include <hip/hip_runtime.h>
#include <math.h>

#define BATCH 2
#define NTOK  256
#define NATOM 2048
#define TL 128
#define TM 64
#define NPB 512          // pair blocks per batch = (NATOM/TL)*(NATOM/TM)
#define TBBUF 1600

__device__ __forceinline__ float frcp(float x)  { return __builtin_amdgcn_rcpf(x); }
__device__ __forceinline__ float fsqrt_(float x){ return __builtin_amdgcn_sqrtf(x); }

__device__ __forceinline__ double wred64(double v) {
    for (int o = 32; o > 0; o >>= 1) v += __shfl_down(v, o, 64);
    return v;
}
__device__ __forceinline__ float fred64(float v) {
    for (int o = 32; o > 0; o >>= 1) v += __shfl_down(v, o, 64);
    return v;
}

// Kabsch R from 17 raw sums: [0]=masksum [1]=wmsum [2..4]=sum wm*X [5..7]=sum wm*G
// [8..16]=sum wm*X_i*G_j.  Returns R (applied to centered G), muX, muG.
__device__ void kabsch_from_sums(const double* sh, float* Rf, float* muf, double* masksum) {
    double wmsum = sh[1];
    double H[3][3];
    for (int i = 0; i < 3; i++)
        for (int j = 0; j < 3; j++)
            H[i][j] = sh[8 + i * 3 + j] - sh[2 + i] * sh[5 + j] / wmsum;
    double A[3][3];
    for (int j = 0; j < 3; j++) for (int k = 0; k < 3; k++) {
        double s = 0; for (int i = 0; i < 3; i++) s += H[i][j] * H[i][k];
        A[j][k] = s;
    }
    double V[3][3] = {{1, 0, 0}, {0, 1, 0}, {0, 0, 1}};
    for (int sweep = 0; sweep < 10; ++sweep) {
        double off = fabs(A[0][1]) + fabs(A[0][2]) + fabs(A[1][2]);
        double diag = fabs(A[0][0]) + fabs(A[1][1]) + fabs(A[2][2]);
        if (off < 1e-13 * (diag + 1e-300)) break;
        for (int pi = 0; pi < 3; ++pi) {
            int pp_ = (pi == 2) ? 1 : 0;
            int qq_ = (pi == 0) ? 1 : 2;
            double apq = A[pp_][qq_];
            if (fabs(apq) < 1e-300) continue;
            double theta = (A[qq_][qq_] - A[pp_][pp_]) / (2.0 * apq);
            double t_ = ((theta >= 0) ? 1.0 : -1.0) / (fabs(theta) + sqrt(theta * theta + 1.0));
            double c_ = 1.0 / sqrt(t_ * t_ + 1.0), sn = t_ * c_;
            for (int k = 0; k < 3; k++) { double akp = A[k][pp_], akq = A[k][qq_];
                A[k][pp_] = c_ * akp - sn * akq; A[k][qq_] = sn * akp + c_ * akq; }
            for (int k = 0; k < 3; k++) { double apk = A[pp_][k], aqk = A[qq_][k];
                A[pp_][k] = c_ * apk - sn * aqk; A[qq_][k] = sn * apk + c_ * aqk; }
            for (int k = 0; k < 3; k++) { double vkp = V[k][pp_], vkq = V[k][qq_];
                V[k][pp_] = c_ * vkp - sn * vkq; V[k][qq_] = sn * vkp + c_ * vkq; }
        }
    }
    double lam[3] = {A[0][0], A[1][1], A[2][2]};
    int idx[3] = {0, 1, 2};
    for (int i = 0; i < 2; i++) for (int j = i + 1; j < 3; j++)
        if (lam[idx[j]] > lam[idx[i]]) { int tsw = idx[i]; idx[i] = idx[j]; idx[j] = tsw; }
    double Vs[3][3], sv[3];
    for (int k = 0; k < 3; k++) {
        sv[k] = sqrt(fmax(lam[idx[k]], 0.0));
        for (int i = 0; i < 3; i++) Vs[i][k] = V[i][idx[k]];
    }
    double U[3][3] = {{1, 0, 0}, {0, 1, 0}, {0, 0, 1}};
    for (int k = 0; k < 3; k++) {
        if (sv[k] > 1e-12 * sv[0] + 1e-300) {
            for (int i = 0; i < 3; i++) {
                double s = 0; for (int j = 0; j < 3; j++) s += H[i][j] * Vs[j][k];
                U[i][k] = s / sv[k];
            }
        } else if (k == 2) {
            U[0][2] = U[1][0] * U[2][1] - U[2][0] * U[1][1];
            U[1][2] = U[2][0] * U[0][1] - U[0][0] * U[2][1];
            U[2][2] = U[0][0] * U[1][1] - U[1][0] * U[0][1];
        }
    }
    double R0[3][3];
    for (int i = 0; i < 3; i++) for (int j = 0; j < 3; j++) {
        double s = 0; for (int k = 0; k < 3; k++) s += U[i][k] * Vs[j][k];
        R0[i][j] = s;
    }
    double det = R0[0][0] * (R0[1][1] * R0[2][2] - R0[1][2] * R0[2][1])
               - R0[0][1] * (R0[1][0] * R0[2][2] - R0[1][2] * R0[2][0])
               + R0[0][2] * (R0[1][0] * R0[2][1] - R0[1][1] * R0[2][0]);
    double dk[3] = {1.0, 1.0, (det < 0.0) ? -1.0 : 1.0};
    for (int i = 0; i < 3; i++) for (int j = 0; j < 3; j++) {
        double s = 0; for (int k = 0; k < 3; k++) s += U[i][k] * dk[k] * Vs[j][k];
        Rf[i * 3 + j] = (float)s;
    }
    for (int i = 0; i < 3; i++) {
        muf[i]     = (float)(sh[2 + i] / wmsum);
        muf[3 + i] = (float)(sh[5 + i] / wmsum);
    }
    *masksum = sh[0];
}

// ============ pairwise: inline token prep + bond loss + smooth LDDT ============
// Writes 4 partial sums per block to its own ws slot (no atomics, no zero-init dep).
__global__ __launch_bounds__(256) void pair_kernel(
    const float* __restrict__ x, const float* __restrict__ gt,
    const float* __restrict__ gmask, const float* __restrict__ tb,
    const float* __restrict__ is_p, const float* __restrict__ is_d,
    const float* __restrict__ is_r, const float* __restrict__ is_l,
    const float* __restrict__ tok_mask, const int* __restrict__ npt,
    float* __restrict__ partials)
{
    int b = blockIdx.z;
    int l0 = blockIdx.x * TL, m0 = blockIdx.y * TM;
    int tid = threadIdx.x;

    __shared__ int   s_cum[NTOK];
    __shared__ float s_isl[NTOK], s_poly[NTOK], s_nuc[NTOK], s_tmk[NTOK];
    __shared__ int   s_wsum[4];
    __shared__ float4 s_lx[TL], s_lg[TL], s_mx[TM], s_mg[TM];
    __shared__ float s_lnuc[TL];
    __shared__ int   s_ltok[TL], s_mtok[TM], s_lrow[TL], s_mrel[TM];
    __shared__ float s_tb[TBBUF];
    __shared__ int   s_info[6];
    __shared__ float s_pred[4][4];

    // ---- inline token prep: shuffle-scan cumsum + features ----
    {
        int n = npt[b * NTOK + tid];
        int lane = tid & 63, wv = tid >> 6;
        int v = n;
        #pragma unroll
        for (int o = 1; o < 64; o <<= 1) {
            int u = __shfl_up(v, o, 64);
            if (lane >= o) v += u;
        }
        if (lane == 63) s_wsum[wv] = v;
        float pd = is_d[b * NTOK + tid], pr = is_r[b * NTOK + tid];
        float pp = is_p[b * NTOK + tid], pl = is_l[b * NTOK + tid];
        s_isl[tid]  = pl;
        s_poly[tid] = pp + pd + pr;
        s_nuc[tid]  = pd + pr;
        s_tmk[tid]  = tok_mask[b * NTOK + tid];
        __syncthreads();
        int pref = 0;
        for (int w = 0; w < wv; w++) pref += s_wsum[w];
        s_cum[tid] = v + pref;
    }
    __syncthreads();
    int total = s_cum[NTOK - 1];

    const float* Xb = x + (size_t)b * NATOM * 3;
    const float* Gb = gt + (size_t)b * NATOM * 3;
    const float* Mb = gmask + (size_t)b * NATOM;

    // ---- stage tile atoms ----
    if (tid < TL) {
        int l = l0 + tid;
        int tok = 0; float oh = 0.0f;
        if (l < total) {
            int lo = 0, hi = NTOK - 1;
            while (lo < hi) { int mid = (lo + hi) >> 1; if (s_cum[mid] > l) hi = mid; else lo = mid + 1; }
            tok = lo; oh = s_tmk[tok];
        }
        float ml = Mb[l];
        s_lx[tid] = make_float4(Xb[l * 3], Xb[l * 3 + 1], Xb[l * 3 + 2], ml);
        s_lg[tid] = make_float4(Gb[l * 3], Gb[l * 3 + 1], Gb[l * 3 + 2], s_isl[tok] * oh * ml);
        s_lnuc[tid] = s_nuc[tok] * oh;
        s_ltok[tid] = tok;
    } else if (tid < TL + TM) {
        int i = tid - TL, m = m0 + i;
        int tok = 0; float oh = 0.0f;
        if (m < total) {
            int lo = 0, hi = NTOK - 1;
            while (lo < hi) { int mid = (lo + hi) >> 1; if (s_cum[mid] > m) hi = mid; else lo = mid + 1; }
            tok = lo; oh = s_tmk[tok];
        }
        float mm = Mb[m];
        s_mx[i] = make_float4(Xb[m * 3], Xb[m * 3 + 1], Xb[m * 3 + 2], mm);
        s_mg[i] = make_float4(Gb[m * 3], Gb[m * 3 + 1], Gb[m * 3 + 2], s_poly[tok] * oh * mm);
        s_mtok[i] = tok;
    }
    __syncthreads();
    if (tid == 0) {
        int tl0 = s_ltok[0], tl1 = s_ltok[TL - 1];
        int tm0 = s_mtok[0], tm1 = s_mtok[TM - 1];
        int spanL = tl1 - tl0 + 1, spanM = tm1 - tm0 + 1;
        int stride = spanM | 1;
        int fits = (spanL * stride <= TBBUF);
        s_info[0] = fits; s_info[1] = stride; s_info[2] = spanM;
        s_info[3] = tl0; s_info[4] = tm0; s_info[5] = spanL;
    }
    __syncthreads();
    int fits = s_info[0], stride = s_info[1], spanM = s_info[2];
    int tl0 = s_info[3], tm0 = s_info[4], spanL = s_info[5];
    if (tid < TL) {
        int tk = s_ltok[tid];
        s_lrow[tid] = fits ? min(max(tk - tl0, 0), spanL - 1) * stride : tk * NTOK;
    } else if (tid < TL + TM) {
        int tk = s_mtok[tid - TL];
        s_mrel[tid - TL] = fits ? min(max(tk - tm0, 0), spanM - 1) : tk;
    }
    const float* tbg = tb + (size_t)b * NTOK * NTOK;
    if (fits) {
        int cnt = spanL * stride;
        for (int i = tid; i < cnt; i += 256) {
            int r = i / stride, cc = i - r * stride;
            if (cc < spanM) s_tb[i] = tbg[(tl0 + r) * NTOK + tm0 + cc];
        }
    }
    __syncthreads();

    // ---- main loop: 4 l-atoms x 8 m-atoms per thread ----
    int lt = tid & 31, mg = tid >> 5;     // mg in [0,8)
    float4 lxv[4], lgv[4]; float lnu[4]; int lrw[4], gli[4];
    #pragma unroll
    for (int k = 0; k < 4; k++) {
        int li = lt + 32 * k;
        lxv[k] = s_lx[li]; lgv[k] = s_lg[li];
        lnu[k] = s_lnuc[li]; lrw[k] = s_lrow[li]; gli[k] = l0 + li;
    }
    float bnum = 0.f, bden = 0.f, ce = 0.f, cs = 0.f;
    const float k1 = 0.60653066f, k2 = 0.36787944f, k3 = 0.13533528f, k4 = 0.018315639f;

    auto body = [&](auto ldtb) {
        int mstart = mg * 8;
        #pragma unroll 2
        for (int j = 0; j < 8; j++) {
            int m = mstart + j;
            float4 mxv = s_mx[m], mgv = s_mg[m];
            int mrel = s_mrel[m];
            int gmi = m0 + m;
            #pragma unroll
            for (int k = 0; k < 4; k++) {
                float dx0 = lxv[k].x - mxv.x, dx1 = lxv[k].y - mxv.y, dx2 = lxv[k].z - mxv.z;
                float dg0 = lgv[k].x - mgv.x, dg1 = lgv[k].y - mgv.y, dg2 = lgv[k].z - mgv.z;
                float dxv = fsqrt_(fmaf(dx2, dx2, fmaf(dx1, dx1, fmaf(dx0, dx0, 1e-12f))));
                float dgv = fsqrt_(fmaf(dg2, dg2, fmaf(dg1, dg1, fmaf(dg0, dg0, 1e-12f))));
                float diff = dxv - dgv;
                float tbv = ldtb(lrw[k], mrel);
                float bmv = tbv * (lgv[k].w * mgv.w);
                bden += bmv;
                bnum = fmaf(diff * diff, bmv, bnum);
                float d = fabsf(diff);
                float u = __expf(d);              // sig(a-d) = 1/(1 + e^d * e^-a)
                float e1 = frcp(fmaf(u, k1, 1.0f));
                float e2 = frcp(fmaf(u, k2, 1.0f));
                float e3 = frcp(fmaf(u, k3, 1.0f));
                float e4 = frcp(fmaf(u, k4, 1.0f));
                float es = (e1 + e2) + (e3 + e4);
                float pm = lxv[k].w * mxv.w;
                float ccv = dgv < 30.0f ? (dgv < 15.0f ? 1.0f : lnu[k]) : 0.0f;
                float pm2 = (gli[k] != gmi) ? pm : 0.0f;
                float cm2 = ccv * pm2;
                cs += cm2;
                ce = fmaf(cm2 * 0.25f, es, ce);
            }
        }
    };
    if (fits) body([&](int r, int c) -> float { return s_tb[r + c]; });
    else      body([&](int r, int c) -> float { return tbg[r + c]; });

    // ---- block reduction -> private ws slot ----
    float vals[4] = {bnum, bden, ce, cs};
    int lane = tid & 63, wv = tid >> 6;
    #pragma unroll
    for (int q = 0; q < 4; q++) {
        float v = fred64(vals[q]);
        if (lane == 0) s_pred[wv][q] = v;
    }
    __syncthreads();
    if (tid < 4) {
        float v = s_pred[0][tid] + s_pred[1][tid] + s_pred[2][tid] + s_pred[3][tid];
        int slot = blockIdx.y * gridDim.x + blockIdx.x;   // [0, NPB)
        partials[((size_t)b * NPB + slot) * 4 + tid] = v;
    }
}

// ============ tail: align (Kabsch+MSE) per batch + reduce partials + combine ============
// 1 block / 256 threads; waves 0-1 handle batch 0, waves 2-3 handle batch 1.
__global__ __launch_bounds__(256) void tail_kernel(
    const float* __restrict__ x, const float* __restrict__ gt,
    const float* __restrict__ gmask,
    const float* __restrict__ is_p, const float* __restrict__ is_d,
    const float* __restrict__ is_r, const float* __restrict__ is_l,
    const float* __restrict__ tok_mask, const int* __restrict__ npt,
    const float* __restrict__ t, const float* __restrict__ partials,
    float* __restrict__ out)
{
    int tid = threadIdx.x;
    int b   = tid >> 7;          // batch
    int ht  = tid & 127;         // thread within half
    int lane = tid & 63;
    int hwv  = (tid >> 6) & 1;   // wave within half

    __shared__ int    s_cum[2][NTOK];
    __shared__ float  s_wt[2][NTOK];
    __shared__ int    s_ws[2][2];
    __shared__ float  s_aw[2][NATOM];        // 16 KB: per-atom weight cache
    __shared__ double s_dred[2][2][17];
    __shared__ float  s_Rf[2][9], s_muf[2][6];
    __shared__ double s_msum[2];
    __shared__ double s_mred[2][2];
    __shared__ double s_pr[2][2][4];
    __shared__ float  s_loss[2];

    // ---- token scan (2 tokens per thread) + weights ----
    {
        int t0 = 2 * ht, t1 = t0 + 1;
        int n0 = npt[b * NTOK + t0], n1 = npt[b * NTOK + t1];
        int v = n0 + n1;
        #pragma unroll
        for (int o = 1; o < 64; o <<= 1) {
            int u = __shfl_up(v, o, 64);
            if (lane >= o) v += u;
        }
        if (lane == 63) s_ws[b][hwv] = v;
        float d0 = is_d[b * NTOK + t0], r0 = is_r[b * NTOK + t0], l0v = is_l[b * NTOK + t0];
        float d1 = is_d[b * NTOK + t1], r1 = is_r[b * NTOK + t1], l1v = is_l[b * NTOK + t1];
        s_wt[b][t0] = (1.0f + 5.0f * d0 + 5.0f * r0 + 10.0f * l0v) * tok_mask[b * NTOK + t0];
        s_wt[b][t1] = (1.0f + 5.0f * d1 + 5.0f * r1 + 10.0f * l1v) * tok_mask[b * NTOK + t1];
        __syncthreads();
        int pref = (hwv == 1) ? s_ws[b][0] : 0;
        int c1 = v + pref;
        s_cum[b][t1] = c1;
        s_cum[b][t0] = c1 - n1;
    }
    __syncthreads();
    int total = s_cum[b][NTOK - 1];

    const float* X = x + (size_t)b * NATOM * 3;
    const float* G = gt + (size_t)b * NATOM * 3;
    const float* M = gmask + (size_t)b * NATOM;

    // ---- pass 1: 17 raw sums for Kabsch ----
    double p[17];
    #pragma unroll
    for (int q = 0; q < 17; q++) p[q] = 0.0;
    for (int a = ht; a < NATOM; a += 128) {
        float w = 0.0f;
        if (a < total) {
            int lo = 0, hi = NTOK - 1;
            while (lo < hi) { int mid = (lo + hi) >> 1; if (s_cum[b][mid] > a) hi = mid; else lo = mid + 1; }
            w = s_wt[b][lo];
        }
        s_aw[b][a] = w;
        double m = M[a], wm = (double)w * m;
        double x0 = X[a * 3], x1 = X[a * 3 + 1], x2 = X[a * 3 + 2];
        double g0 = G[a * 3], g1 = G[a * 3 + 1], g2 = G[a * 3 + 2];
        p[0] += m; p[1] += wm;
        p[2] += wm * x0; p[3] += wm * x1; p[4] += wm * x2;
        p[5] += wm * g0; p[6] += wm * g1; p[7] += wm * g2;
        p[8]  += wm * x0 * g0; p[9]  += wm * x0 * g1; p[10] += wm * x0 * g2;
        p[11] += wm * x1 * g0; p[12] += wm * x1 * g1; p[13] += wm * x1 * g2;
        p[14] += wm * x2 * g0; p[15] += wm * x2 * g1; p[16] += wm * x2 * g2;
    }
    #pragma unroll
    for (int q = 0; q < 17; q++) {
        double v = wred64(p[q]);
        if (lane == 0) s_dred[b][hwv][q] = v;
    }
    __syncthreads();
    if (ht == 0) {
        double sh[17];
        for (int q = 0; q < 17; q++) sh[q] = s_dred[b][0][q] + s_dred[b][1][q];
        double ms;
        kabsch_from_sums(sh, s_Rf[b], s_muf[b], &ms);
        s_msum[b] = ms;
    }
    __syncthreads();

    // ---- pass 2: weighted MSE with aligned GT ----
    float R00 = s_Rf[b][0], R01 = s_Rf[b][1], R02 = s_Rf[b][2];
    float R10 = s_Rf[b][3], R11 = s_Rf[b][4], R12 = s_Rf[b][5];
    float R20 = s_Rf[b][6], R21 = s_Rf[b][7], R22 = s_Rf[b][8];
    float mux0 = s_muf[b][0], mux1 = s_muf[b][1], mux2 = s_muf[b][2];
    float mug0 = s_muf[b][3], mug1 = s_muf[b][4], mug2 = s_muf[b][5];
    double part = 0.0;
    for (int a = ht; a < NATOM; a += 128) {
        float w = s_aw[b][a], m = M[a];
        float gc0 = G[a * 3] - mug0, gc1 = G[a * 3 + 1] - mug1, gc2 = G[a * 3 + 2] - mug2;
        float al0 = R00 * gc0 + R01 * gc1 + R02 * gc2 + mux0;
        float al1 = R10 * gc0 + R11 * gc1 + R12 * gc2 + mux1;
        float al2 = R20 * gc0 + R21 * gc1 + R22 * gc2 + mux2;
        float r0 = X[a * 3] - al0, r1 = X[a * 3 + 1] - al1, r2 = X[a * 3 + 2] - al2;
        part += (double)(w * m * (r0 * r0 + r1 * r1 + r2 * r2));
    }
    {
        double v = wred64(part);
        if (lane == 0) s_mred[b][hwv] = v;
    }

    // ---- reduce pair-kernel partials ----
    double pr[4] = {0, 0, 0, 0};
    for (int i = ht; i < NPB; i += 128) {
        const float* q = partials + ((size_t)b * NPB + i) * 4;
        pr[0] += q[0]; pr[1] += q[1]; pr[2] += q[2]; pr[3] += q[3];
    }
    #pragma unroll
    for (int q = 0; q < 4; q++) {
        double v = wred64(pr[q]);
        if (lane == 0) s_pr[b][hwv][q] = v;
    }
    __syncthreads();

    // ---- per-batch combine, then final mean ----
    if (ht == 0) {
        double l_mse  = (s_mred[b][0] + s_mred[b][1]) / (3.0 * s_msum[b]);
        double bnum = s_pr[b][0][0] + s_pr[b][1][0];
        double bden = s_pr[b][0][1] + s_pr[b][1][1];
        double cesum = s_pr[b][0][2] + s_pr[b][1][2];
        double cssum = s_pr[b][0][3] + s_pr[b][1][3];
        double l_bond = bnum / bden;
        double l_lddt = 1.0 - cesum / cssum;
        double tt = t[b];
        double w_t = (tt * tt + 256.0) / ((tt + 16.0) * (tt + 16.0));
        s_loss[b] = (float)(w_t * (l_mse + l_bond) + l_lddt);
    }
    __syncthreads();
    if (tid == 0) out[0] = 0.5f * (s_loss[0] + s_loss[1]);
}

extern "C" void kernel_launch(void* const* d_in, const int* in_sizes, int n_in,
                              void* d_out, int out_size, void* d_ws, size_t ws_size,
                              hipStream_t stream) {
    const float* x     = (const float*)d_in[0];
    const float* gt    = (const float*)d_in[1];
    const float* gmask = (const float*)d_in[2];
    const float* is_p  = (const float*)d_in[3];
    const float* is_d  = (const float*)d_in[4];
    const float* is_r  = (const float*)d_in[5];
    const float* is_l  = (const float*)d_in[6];
    const float* tb    = (const float*)d_in[7];
    const float* tm    = (const float*)d_in[8];
    const int*   npt   = (const int*)d_in[9];
    const float* t     = (const float*)d_in[10];
    float* out = (float*)d_out;

    float* partials = (float*)d_ws;   // [BATCH][NPB][4]

    dim3 pg(NATOM / TL, NATOM / TM, BATCH);   // 16 x 32 x 2 = 1024 blocks
    pair_kernel<<<pg, 256, 0, stream>>>(x, gt, gmask, tb, is_p, is_d, is_r, is_l,
                                        tm, npt, partials);
    tail_kernel<<<1, 256, 0, stream>>>(x, gt, gmask, is_p, is_d, is_r, is_l,
                                       tm, npt, t, partials, out);
}

// Round 4
// 105.834 us; speedup vs baseline: 1.1418x; 1.1418x over previous
//
#include <hip/hip_runtime.h>
#include <math.h>

#define BATCH 2
#define NTOK  256
#define NATOM 2048
#define TL 128
#define TM 64
#define NPB 512          // pair blocks per batch = (NATOM/TL)*(NATOM/TM)
#define TBBUF 1600

__device__ __forceinline__ float frcp(float x)  { return __builtin_amdgcn_rcpf(x); }
__device__ __forceinline__ float fsqrt_(float x){ return __builtin_amdgcn_sqrtf(x); }

__device__ __forceinline__ double wred64(double v) {
    for (int o = 32; o > 0; o >>= 1) v += __shfl_down(v, o, 64);
    return v;
}
__device__ __forceinline__ float fred64(float v) {
    for (int o = 32; o > 0; o >>= 1) v += __shfl_down(v, o, 64);
    return v;
}

// Kabsch R from 17 raw sums: [0]=masksum [1]=wmsum [2..4]=sum wm*X [5..7]=sum wm*G
// [8..16]=sum wm*X_i*G_j.  R applies to centered G; muf = {muX, muG}.
__device__ void kabsch_from_sums(const double* sh, float* Rf, float* muf, double* masksum) {
    double wmsum = sh[1];
    double H[3][3];
    for (int i = 0; i < 3; i++)
        for (int j = 0; j < 3; j++)
            H[i][j] = sh[8 + i * 3 + j] - sh[2 + i] * sh[5 + j] / wmsum;
    double A[3][3];
    for (int j = 0; j < 3; j++) for (int k = 0; k < 3; k++) {
        double s = 0; for (int i = 0; i < 3; i++) s += H[i][j] * H[i][k];
        A[j][k] = s;
    }
    double V[3][3] = {{1, 0, 0}, {0, 1, 0}, {0, 0, 1}};
    for (int sweep = 0; sweep < 8; ++sweep) {
        double off = fabs(A[0][1]) + fabs(A[0][2]) + fabs(A[1][2]);
        double diag = fabs(A[0][0]) + fabs(A[1][1]) + fabs(A[2][2]);
        if (off < 1e-13 * (diag + 1e-300)) break;
        for (int pi = 0; pi < 3; ++pi) {
            int pp_ = (pi == 2) ? 1 : 0;
            int qq_ = (pi == 0) ? 1 : 2;
            double apq = A[pp_][qq_];
            if (fabs(apq) < 1e-300) continue;
            double theta = (A[qq_][qq_] - A[pp_][pp_]) / (2.0 * apq);
            double t_ = ((theta >= 0) ? 1.0 : -1.0) / (fabs(theta) + sqrt(theta * theta + 1.0));
            double c_ = 1.0 / sqrt(t_ * t_ + 1.0), sn = t_ * c_;
            for (int k = 0; k < 3; k++) { double akp = A[k][pp_], akq = A[k][qq_];
                A[k][pp_] = c_ * akp - sn * akq; A[k][qq_] = sn * akp + c_ * akq; }
            for (int k = 0; k < 3; k++) { double apk = A[pp_][k], aqk = A[qq_][k];
                A[pp_][k] = c_ * apk - sn * aqk; A[qq_][k] = sn * apk + c_ * aqk; }
            for (int k = 0; k < 3; k++) { double vkp = V[k][pp_], vkq = V[k][qq_];
                V[k][pp_] = c_ * vkp - sn * vkq; V[k][qq_] = sn * vkp + c_ * vkq; }
        }
    }
    double lam[3] = {A[0][0], A[1][1], A[2][2]};
    int idx[3] = {0, 1, 2};
    for (int i = 0; i < 2; i++) for (int j = i + 1; j < 3; j++)
        if (lam[idx[j]] > lam[idx[i]]) { int tsw = idx[i]; idx[i] = idx[j]; idx[j] = tsw; }
    double Vs[3][3], sv[3];
    for (int k = 0; k < 3; k++) {
        sv[k] = sqrt(fmax(lam[idx[k]], 0.0));
        for (int i = 0; i < 3; i++) Vs[i][k] = V[i][idx[k]];
    }
    double U[3][3] = {{1, 0, 0}, {0, 1, 0}, {0, 0, 1}};
    for (int k = 0; k < 3; k++) {
        if (sv[k] > 1e-12 * sv[0] + 1e-300) {
            for (int i = 0; i < 3; i++) {
                double s = 0; for (int j = 0; j < 3; j++) s += H[i][j] * Vs[j][k];
                U[i][k] = s / sv[k];
            }
        } else if (k == 2) {
            U[0][2] = U[1][0] * U[2][1] - U[2][0] * U[1][1];
            U[1][2] = U[2][0] * U[0][1] - U[0][0] * U[2][1];
            U[2][2] = U[0][0] * U[1][1] - U[1][0] * U[0][1];
        }
    }
    double R0[3][3];
    for (int i = 0; i < 3; i++) for (int j = 0; j < 3; j++) {
        double s = 0; for (int k = 0; k < 3; k++) s += U[i][k] * Vs[j][k];
        R0[i][j] = s;
    }
    double det = R0[0][0] * (R0[1][1] * R0[2][2] - R0[1][2] * R0[2][1])
               - R0[0][1] * (R0[1][0] * R0[2][2] - R0[1][2] * R0[2][0])
               + R0[0][2] * (R0[1][0] * R0[2][1] - R0[1][1] * R0[2][0]);
    double dk[3] = {1.0, 1.0, (det < 0.0) ? -1.0 : 1.0};
    for (int i = 0; i < 3; i++) for (int j = 0; j < 3; j++) {
        double s = 0; for (int k = 0; k < 3; k++) s += U[i][k] * dk[k] * Vs[j][k];
        Rf[i * 3 + j] = (float)s;
    }
    for (int i = 0; i < 3; i++) {
        muf[i]     = (float)(sh[2 + i] / wmsum);
        muf[3 + i] = (float)(sh[5 + i] / wmsum);
    }
    *masksum = sh[0];
}

struct PairSh {
    int    cum[NTOK];
    float  isl[NTOK], poly[NTOK], nuc[NTOK], tmk[NTOK];
    int    wsum[4];
    float4 lx[TL], lg[TL], mx[TM], mg[TM];
    float  lnuc[TL];
    int    ltok[TL], mtok[TM], lrow[TL], mrel[TM];
    float  tbuf[TBBUF];
    int    info[6];
    float  pred[4][4];
};
struct AlignSh {
    int    cum[NTOK];
    float  wt[NTOK];
    int    wsum[4];
    float  aw[NATOM];
    double dred[4][17];
    float  Rf[9], muf[6];
    double msum;
    double mred[4];
};

// ============ fused: 1024 pair-tile blocks + 2 align blocks (one launch) ============
__global__ __launch_bounds__(256) void pair_align_kernel(
    const float* __restrict__ x, const float* __restrict__ gt,
    const float* __restrict__ gmask, const float* __restrict__ tb,
    const float* __restrict__ is_p, const float* __restrict__ is_d,
    const float* __restrict__ is_r, const float* __restrict__ is_l,
    const float* __restrict__ tok_mask, const int* __restrict__ npt,
    float4* __restrict__ partials4, float* __restrict__ lmse)
{
    __shared__ __align__(16) char smem[sizeof(PairSh) > sizeof(AlignSh) ? sizeof(PairSh) : sizeof(AlignSh)];
    int id = blockIdx.x;
    int tid = threadIdx.x;
    int lane = tid & 63, wv = tid >> 6;

    if (id < 2 * NPB) {
        // ================= pair path =================
        PairSh* s = (PairSh*)smem;
        int b = id >> 9;
        int slot = id & (NPB - 1);
        int l0 = (slot & 15) * TL;
        int m0 = (slot >> 4) * TM;

        // ---- inline token prep: shuffle-scan cumsum + features ----
        {
            int n = npt[b * NTOK + tid];
            int v = n;
            #pragma unroll
            for (int o = 1; o < 64; o <<= 1) {
                int u = __shfl_up(v, o, 64);
                if (lane >= o) v += u;
            }
            if (lane == 63) s->wsum[wv] = v;
            float pd = is_d[b * NTOK + tid], pr = is_r[b * NTOK + tid];
            float pp = is_p[b * NTOK + tid], pl = is_l[b * NTOK + tid];
            s->isl[tid]  = pl;
            s->poly[tid] = pp + pd + pr;
            s->nuc[tid]  = pd + pr;
            s->tmk[tid]  = tok_mask[b * NTOK + tid];
            __syncthreads();
            int pref = 0;
            for (int w = 0; w < wv; w++) pref += s->wsum[w];
            s->cum[tid] = v + pref;
        }
        __syncthreads();
        int total = s->cum[NTOK - 1];

        const float* Xb = x + (size_t)b * NATOM * 3;
        const float* Gb = gt + (size_t)b * NATOM * 3;
        const float* Mb = gmask + (size_t)b * NATOM;

        // ---- stage tile atoms ----
        if (tid < TL) {
            int l = l0 + tid;
            int tok = 0; float oh = 0.0f;
            if (l < total) {
                int lo = 0, hi = NTOK - 1;
                while (lo < hi) { int mid = (lo + hi) >> 1; if (s->cum[mid] > l) hi = mid; else lo = mid + 1; }
                tok = lo; oh = s->tmk[tok];
            }
            float ml = Mb[l];
            s->lx[tid] = make_float4(Xb[l * 3], Xb[l * 3 + 1], Xb[l * 3 + 2], ml);
            s->lg[tid] = make_float4(Gb[l * 3], Gb[l * 3 + 1], Gb[l * 3 + 2], s->isl[tok] * oh * ml);
            s->lnuc[tid] = s->nuc[tok] * oh;
            s->ltok[tid] = tok;
        } else if (tid < TL + TM) {
            int i = tid - TL, m = m0 + i;
            int tok = 0; float oh = 0.0f;
            if (m < total) {
                int lo = 0, hi = NTOK - 1;
                while (lo < hi) { int mid = (lo + hi) >> 1; if (s->cum[mid] > m) hi = mid; else lo = mid + 1; }
                tok = lo; oh = s->tmk[tok];
            }
            float mm = Mb[m];
            s->mx[i] = make_float4(Xb[m * 3], Xb[m * 3 + 1], Xb[m * 3 + 2], mm);
            s->mg[i] = make_float4(Gb[m * 3], Gb[m * 3 + 1], Gb[m * 3 + 2], s->poly[tok] * oh * mm);
            s->mtok[i] = tok;
        }
        __syncthreads();
        if (tid == 0) {
            int tl0 = s->ltok[0], tl1 = s->ltok[TL - 1];
            int tm0 = s->mtok[0], tm1 = s->mtok[TM - 1];
            int spanL = tl1 - tl0 + 1, spanM = tm1 - tm0 + 1;
            int stride = spanM | 1;
            int fits = (spanL * stride <= TBBUF);
            s->info[0] = fits; s->info[1] = stride; s->info[2] = spanM;
            s->info[3] = tl0; s->info[4] = tm0; s->info[5] = spanL;
        }
        __syncthreads();
        int fits = s->info[0], stride = s->info[1], spanM = s->info[2];
        int tl0 = s->info[3], tm0 = s->info[4], spanL = s->info[5];
        if (tid < TL) {
            int tk = s->ltok[tid];
            s->lrow[tid] = fits ? min(max(tk - tl0, 0), spanL - 1) * stride : tk * NTOK;
        } else if (tid < TL + TM) {
            int tk = s->mtok[tid - TL];
            s->mrel[tid - TL] = fits ? min(max(tk - tm0, 0), spanM - 1) : tk;
        }
        const float* tbg = tb + (size_t)b * NTOK * NTOK;
        if (fits) {
            int cnt = spanL * stride;
            for (int i = tid; i < cnt; i += 256) {
                int r = i / stride, cc = i - r * stride;
                if (cc < spanM) s->tbuf[i] = tbg[(tl0 + r) * NTOK + tm0 + cc];
            }
        }
        __syncthreads();

        // ---- main loop: 4 l-atoms x 8 m-atoms per thread ----
        int lt = tid & 31, mg = tid >> 5;     // mg in [0,8)
        float4 lxv[4], lgv[4]; float lnu[4]; int lrw[4], gli[4];
        #pragma unroll
        for (int k = 0; k < 4; k++) {
            int li = lt + 32 * k;
            lxv[k] = s->lx[li]; lgv[k] = s->lg[li];
            lnu[k] = s->lnuc[li]; lrw[k] = s->lrow[li]; gli[k] = l0 + li;
        }
        float bnum = 0.f, bden = 0.f, ce = 0.f, cs = 0.f;
        const float k1 = 0.60653066f, k2 = 0.36787944f, k3 = 0.13533528f, k4 = 0.018315639f;

        auto body = [&](auto ldtb) {
            int mstart = mg * 8;
            #pragma unroll 2
            for (int j = 0; j < 8; j++) {
                int m = mstart + j;
                float4 mxv = s->mx[m], mgv = s->mg[m];
                int mrel = s->mrel[m];
                int gmi = m0 + m;
                #pragma unroll
                for (int k = 0; k < 4; k++) {
                    float dx0 = lxv[k].x - mxv.x, dx1 = lxv[k].y - mxv.y, dx2 = lxv[k].z - mxv.z;
                    float dg0 = lgv[k].x - mgv.x, dg1 = lgv[k].y - mgv.y, dg2 = lgv[k].z - mgv.z;
                    float dxv = fsqrt_(fmaf(dx2, dx2, fmaf(dx1, dx1, fmaf(dx0, dx0, 1e-12f))));
                    float dgv = fsqrt_(fmaf(dg2, dg2, fmaf(dg1, dg1, fmaf(dg0, dg0, 1e-12f))));
                    float diff = dxv - dgv;
                    float tbv = ldtb(lrw[k], mrel);
                    float bmv = tbv * (lgv[k].w * mgv.w);
                    bden += bmv;
                    bnum = fmaf(diff * diff, bmv, bnum);
                    float d = fabsf(diff);
                    float u = __expf(d);              // sig(a-d) = 1/(1 + e^d * e^-a)
                    float e1 = frcp(fmaf(u, k1, 1.0f));
                    float e2 = frcp(fmaf(u, k2, 1.0f));
                    float e3 = frcp(fmaf(u, k3, 1.0f));
                    float e4 = frcp(fmaf(u, k4, 1.0f));
                    float es = (e1 + e2) + (e3 + e4);
                    float pm = lxv[k].w * mxv.w;
                    float ccv = dgv < 30.0f ? (dgv < 15.0f ? 1.0f : lnu[k]) : 0.0f;
                    float pm2 = (gli[k] != gmi) ? pm : 0.0f;
                    float cm2 = ccv * pm2;
                    cs += cm2;
                    ce = fmaf(cm2 * 0.25f, es, ce);
                }
            }
        };
        if (fits) body([&](int r, int c) -> float { return s->tbuf[r + c]; });
        else      body([&](int r, int c) -> float { return tbg[r + c]; });

        // ---- block reduction -> one float4 store to private ws slot ----
        float vals[4] = {bnum, bden, ce, cs};
        #pragma unroll
        for (int q = 0; q < 4; q++) {
            float v = fred64(vals[q]);
            if (lane == 0) s->pred[wv][q] = v;
        }
        __syncthreads();
        if (tid == 0) {
            float4 o;
            o.x = s->pred[0][0] + s->pred[1][0] + s->pred[2][0] + s->pred[3][0];
            o.y = s->pred[0][1] + s->pred[1][1] + s->pred[2][1] + s->pred[3][1];
            o.z = s->pred[0][2] + s->pred[1][2] + s->pred[2][2] + s->pred[3][2];
            o.w = s->pred[0][3] + s->pred[1][3] + s->pred[2][3] + s->pred[3][3];
            partials4[(size_t)b * NPB + slot] = o;
        }
    } else {
        // ================= align path (one block per batch) =================
        AlignSh* s = (AlignSh*)smem;
        int b = id - 2 * NPB;

        // ---- token scan + per-token weight ----
        {
            int n = npt[b * NTOK + tid];
            int v = n;
            #pragma unroll
            for (int o = 1; o < 64; o <<= 1) {
                int u = __shfl_up(v, o, 64);
                if (lane >= o) v += u;
            }
            if (lane == 63) s->wsum[wv] = v;
            float pd = is_d[b * NTOK + tid], pr = is_r[b * NTOK + tid];
            float pl = is_l[b * NTOK + tid];
            s->wt[tid] = (1.0f + 5.0f * pd + 5.0f * pr + 10.0f * pl) * tok_mask[b * NTOK + tid];
            __syncthreads();
            int pref = 0;
            for (int w = 0; w < wv; w++) pref += s->wsum[w];
            s->cum[tid] = v + pref;
        }
        __syncthreads();
        int total = s->cum[NTOK - 1];

        const float* X = x + (size_t)b * NATOM * 3;
        const float* G = gt + (size_t)b * NATOM * 3;
        const float* M = gmask + (size_t)b * NATOM;

        // ---- pass 1: 17 raw sums ----
        double p[17];
        #pragma unroll
        for (int q = 0; q < 17; q++) p[q] = 0.0;
        for (int a = tid; a < NATOM; a += 256) {
            float w = 0.0f;
            if (a < total) {
                int lo = 0, hi = NTOK - 1;
                while (lo < hi) { int mid = (lo + hi) >> 1; if (s->cum[mid] > a) hi = mid; else lo = mid + 1; }
                w = s->wt[lo];
            }
            s->aw[a] = w;
            double m = M[a], wm = (double)w * m;
            double x0 = X[a * 3], x1 = X[a * 3 + 1], x2 = X[a * 3 + 2];
            double g0 = G[a * 3], g1 = G[a * 3 + 1], g2 = G[a * 3 + 2];
            p[0] += m; p[1] += wm;
            p[2] += wm * x0; p[3] += wm * x1; p[4] += wm * x2;
            p[5] += wm * g0; p[6] += wm * g1; p[7] += wm * g2;
            p[8]  += wm * x0 * g0; p[9]  += wm * x0 * g1; p[10] += wm * x0 * g2;
            p[11] += wm * x1 * g0; p[12] += wm * x1 * g1; p[13] += wm * x1 * g2;
            p[14] += wm * x2 * g0; p[15] += wm * x2 * g1; p[16] += wm * x2 * g2;
        }
        #pragma unroll
        for (int q = 0; q < 17; q++) {
            double v = wred64(p[q]);
            if (lane == 0) s->dred[wv][q] = v;
        }
        __syncthreads();
        if (tid == 0) {
            double sh[17];
            for (int q = 0; q < 17; q++)
                sh[q] = s->dred[0][q] + s->dred[1][q] + s->dred[2][q] + s->dred[3][q];
            double ms;
            kabsch_from_sums(sh, s->Rf, s->muf, &ms);
            s->msum = ms;
        }
        __syncthreads();

        // ---- pass 2: weighted MSE ----
        float R00 = s->Rf[0], R01 = s->Rf[1], R02 = s->Rf[2];
        float R10 = s->Rf[3], R11 = s->Rf[4], R12 = s->Rf[5];
        float R20 = s->Rf[6], R21 = s->Rf[7], R22 = s->Rf[8];
        float mux0 = s->muf[0], mux1 = s->muf[1], mux2 = s->muf[2];
        float mug0 = s->muf[3], mug1 = s->muf[4], mug2 = s->muf[5];
        double part = 0.0;
        for (int a = tid; a < NATOM; a += 256) {
            float w = s->aw[a], m = M[a];
            float gc0 = G[a * 3] - mug0, gc1 = G[a * 3 + 1] - mug1, gc2 = G[a * 3 + 2] - mug2;
            float al0 = R00 * gc0 + R01 * gc1 + R02 * gc2 + mux0;
            float al1 = R10 * gc0 + R11 * gc1 + R12 * gc2 + mux1;
            float al2 = R20 * gc0 + R21 * gc1 + R22 * gc2 + mux2;
            float r0 = X[a * 3] - al0, r1 = X[a * 3 + 1] - al1, r2 = X[a * 3 + 2] - al2;
            part += (double)(w * m * (r0 * r0 + r1 * r1 + r2 * r2));
        }
        {
            double v = wred64(part);
            if (lane == 0) s->mred[wv] = v;
        }
        __syncthreads();
        if (tid == 0)
            lmse[b] = (float)((s->mred[0] + s->mred[1] + s->mred[2] + s->mred[3]) / (3.0 * s->msum));
    }
}

// ============ final: reduce pair partials + combine ============
__global__ __launch_bounds__(256) void final_kernel(
    const float4* __restrict__ partials4, const float* __restrict__ lmse,
    const float* __restrict__ t, float* __restrict__ out)
{
    int tid = threadIdx.x, lane = tid & 63, wv = tid >> 6;
    double pr[2][4] = {{0, 0, 0, 0}, {0, 0, 0, 0}};
    #pragma unroll
    for (int b = 0; b < BATCH; b++)
        for (int sI = tid; sI < NPB; sI += 256) {
            float4 v = partials4[(size_t)b * NPB + sI];
            pr[b][0] += v.x; pr[b][1] += v.y; pr[b][2] += v.z; pr[b][3] += v.w;
        }
    __shared__ double sred[4][8];
    #pragma unroll
    for (int b = 0; b < BATCH; b++)
        #pragma unroll
        for (int q = 0; q < 4; q++) {
            double v = wred64(pr[b][q]);
            if (lane == 0) sred[wv][b * 4 + q] = v;
        }
    __syncthreads();
    if (tid == 0) {
        double tot = 0.0;
        for (int b = 0; b < BATCH; b++) {
            double bn = 0, bd = 0, ce = 0, cs = 0;
            for (int w = 0; w < 4; w++) {
                bn += sred[w][b * 4 + 0]; bd += sred[w][b * 4 + 1];
                ce += sred[w][b * 4 + 2]; cs += sred[w][b * 4 + 3];
            }
            double l_bond = bn / bd;
            double l_lddt = 1.0 - ce / cs;
            double tt = t[b];
            double w_t = (tt * tt + 256.0) / ((tt + 16.0) * (tt + 16.0));
            tot += w_t * ((double)lmse[b] + l_bond) + l_lddt;
        }
        out[0] = (float)(tot / (double)BATCH);
    }
}

extern "C" void kernel_launch(void* const* d_in, const int* in_sizes, int n_in,
                              void* d_out, int out_size, void* d_ws, size_t ws_size,
                              hipStream_t stream) {
    const float* x     = (const float*)d_in[0];
    const float* gt    = (const float*)d_in[1];
    const float* gmask = (const float*)d_in[2];
    const float* is_p  = (const float*)d_in[3];
    const float* is_d  = (const float*)d_in[4];
    const float* is_r  = (const float*)d_in[5];
    const float* is_l  = (const float*)d_in[6];
    const float* tb    = (const float*)d_in[7];
    const float* tm    = (const float*)d_in[8];
    const int*   npt   = (const int*)d_in[9];
    const float* t     = (const float*)d_in[10];
    float* out = (float*)d_out;

    float4* partials4 = (float4*)d_ws;                                    // [BATCH][NPB]
    float*  lmse      = (float*)((char*)d_ws + (size_t)BATCH * NPB * sizeof(float4));

    pair_align_kernel<<<2 * NPB + BATCH, 256, 0, stream>>>(
        x, gt, gmask, tb, is_p, is_d, is_r, is_l, tm, npt, partials4, lmse);
    final_kernel<<<1, 256, 0, stream>>>(partials4, lmse, t, out);
}

// Round 5
// 96.419 us; speedup vs baseline: 1.2533x; 1.0977x over previous
//
#include <hip/hip_runtime.h>
#include <math.h>

#define BATCH 2
#define NTOK  256
#define NATOM 2048
#define TL 128
#define TM 64
#define NPB 512          // pair blocks per batch = (NATOM/TL)*(NATOM/TM)
#define TBBUF 1600

__device__ __forceinline__ float frcp(float x)  { return __builtin_amdgcn_rcpf(x); }
__device__ __forceinline__ float fsqrt_(float x){ return __builtin_amdgcn_sqrtf(x); }

__device__ __forceinline__ double wred64(double v) {
    for (int o = 32; o > 0; o >>= 1) v += __shfl_down(v, o, 64);
    return v;
}
__device__ __forceinline__ float fred64(float v) {
    for (int o = 32; o > 0; o >>= 1) v += __shfl_down(v, o, 64);
    return v;
}

// Kabsch from 17 raw double sums: [0]=masksum [1]=wmsum [2..4]=sum wm*X
// [5..7]=sum wm*G [8..16]=sum wm*X_i*G_j.  R (fp32) applies to centered G.
// fp32 internals: H~1e6, A~1e12 well inside fp32 range; R err ~1e-5 -> l_mse err ~1e-3.
__device__ void kabsch_from_sums(const double* shd, float* Rf, float* muf, double* masksum) {
    double wmsum = shd[1];
    float H[3][3];
    for (int i = 0; i < 3; i++)
        for (int j = 0; j < 3; j++)
            H[i][j] = (float)(shd[8 + i * 3 + j] - shd[2 + i] * shd[5 + j] / wmsum);
    float A[3][3];
    for (int j = 0; j < 3; j++) for (int k = 0; k < 3; k++) {
        float s = 0.f; for (int i = 0; i < 3; i++) s = fmaf(H[i][j], H[i][k], s);
        A[j][k] = s;
    }
    float V[3][3] = {{1, 0, 0}, {0, 1, 0}, {0, 0, 1}};
    for (int sweep = 0; sweep < 6; ++sweep) {
        float off = fabsf(A[0][1]) + fabsf(A[0][2]) + fabsf(A[1][2]);
        float diag = fabsf(A[0][0]) + fabsf(A[1][1]) + fabsf(A[2][2]);
        if (off < 1e-7f * diag) break;
        for (int pi = 0; pi < 3; ++pi) {
            int pp_ = (pi == 2) ? 1 : 0;
            int qq_ = (pi == 0) ? 1 : 2;
            float apq = A[pp_][qq_];
            float sc = fabsf(A[pp_][pp_]) + fabsf(A[qq_][qq_]);
            if (fabsf(apq) <= 1e-9f * sc) continue;
            float theta = (A[qq_][qq_] - A[pp_][pp_]) * 0.5f * frcp(apq);
            float t_ = ((theta >= 0.f) ? 1.0f : -1.0f) * frcp(fabsf(theta) + fsqrt_(fmaf(theta, theta, 1.0f)));
            float c_ = frcp(fsqrt_(fmaf(t_, t_, 1.0f))), sn = t_ * c_;
            for (int k = 0; k < 3; k++) { float akp = A[k][pp_], akq = A[k][qq_];
                A[k][pp_] = c_ * akp - sn * akq; A[k][qq_] = sn * akp + c_ * akq; }
            for (int k = 0; k < 3; k++) { float apk = A[pp_][k], aqk = A[qq_][k];
                A[pp_][k] = c_ * apk - sn * aqk; A[qq_][k] = sn * apk + c_ * aqk; }
            for (int k = 0; k < 3; k++) { float vkp = V[k][pp_], vkq = V[k][qq_];
                V[k][pp_] = c_ * vkp - sn * vkq; V[k][qq_] = sn * vkp + c_ * vkq; }
        }
    }
    float lam[3] = {A[0][0], A[1][1], A[2][2]};
    int idx[3] = {0, 1, 2};
    for (int i = 0; i < 2; i++) for (int j = i + 1; j < 3; j++)
        if (lam[idx[j]] > lam[idx[i]]) { int tsw = idx[i]; idx[i] = idx[j]; idx[j] = tsw; }
    float Vs[3][3], sv[3];
    for (int k = 0; k < 3; k++) {
        sv[k] = fsqrt_(fmaxf(lam[idx[k]], 0.0f));
        for (int i = 0; i < 3; i++) Vs[i][k] = V[i][idx[k]];
    }
    float U[3][3] = {{1, 0, 0}, {0, 1, 0}, {0, 0, 1}};
    for (int k = 0; k < 3; k++) {
        if (sv[k] > 1e-6f * sv[0] + 1e-30f) {
            float inv = frcp(sv[k]);
            for (int i = 0; i < 3; i++) {
                float s = 0.f; for (int j = 0; j < 3; j++) s = fmaf(H[i][j], Vs[j][k], s);
                U[i][k] = s * inv;
            }
        } else if (k == 2) {
            U[0][2] = U[1][0] * U[2][1] - U[2][0] * U[1][1];
            U[1][2] = U[2][0] * U[0][1] - U[0][0] * U[2][1];
            U[2][2] = U[0][0] * U[1][1] - U[1][0] * U[0][1];
        }
    }
    float R0[3][3];
    for (int i = 0; i < 3; i++) for (int j = 0; j < 3; j++) {
        float s = 0.f; for (int k = 0; k < 3; k++) s = fmaf(U[i][k], Vs[j][k], s);
        R0[i][j] = s;
    }
    float det = R0[0][0] * (R0[1][1] * R0[2][2] - R0[1][2] * R0[2][1])
              - R0[0][1] * (R0[1][0] * R0[2][2] - R0[1][2] * R0[2][0])
              + R0[0][2] * (R0[1][0] * R0[2][1] - R0[1][1] * R0[2][0]);
    float s2 = (det < 0.0f) ? -1.0f : 1.0f;
    for (int i = 0; i < 3; i++) for (int j = 0; j < 3; j++)
        Rf[i * 3 + j] = fmaf(U[i][0], Vs[j][0], fmaf(U[i][1], Vs[j][1], s2 * U[i][2] * Vs[j][2]));
    for (int i = 0; i < 3; i++) {
        muf[i]     = (float)(shd[2 + i] / wmsum);
        muf[3 + i] = (float)(shd[5 + i] / wmsum);
    }
    *masksum = shd[0];
}

struct PairSh {
    float  isl[NTOK], poly[NTOK], nuc[NTOK], tmk[NTOK];
    int    wsum[4];
    unsigned short atokp1[NATOM];   // token+1, 0 = invalid atom
    float4 lx[TL], lg[TL], mx[TM], mg[TM];
    float  lnuc[TL];
    int    ltok[TL], mtok[TM], lrow[TL], mrel[TM];
    float  tbuf[TBBUF];
    int    info[6];
    float  pred[4][4];
};
struct AlignSh {
    int    wsum[4];
    float  aw[NATOM];
    double dred[4][17];
    float  Rf[9], muf[6];
    double msum;
    double mred[4];
};

// ============ fused: 2 align blocks (ids 0,1) + 1024 pair-tile blocks ============
__global__ __launch_bounds__(256) void pair_align_kernel(
    const float* __restrict__ x, const float* __restrict__ gt,
    const float* __restrict__ gmask, const float* __restrict__ tb,
    const float* __restrict__ is_p, const float* __restrict__ is_d,
    const float* __restrict__ is_r, const float* __restrict__ is_l,
    const float* __restrict__ tok_mask, const int* __restrict__ npt,
    float4* __restrict__ partials4, float* __restrict__ lmse)
{
    __shared__ __align__(16) char smem[sizeof(PairSh) > sizeof(AlignSh) ? sizeof(PairSh) : sizeof(AlignSh)];
    int id = blockIdx.x;
    int tid = threadIdx.x;
    int lane = tid & 63, wv = tid >> 6;

    if (id >= BATCH) {
        // ================= pair path =================
        PairSh* s = (PairSh*)smem;
        int pid = id - BATCH;
        int b = pid >> 9;
        int slot = pid & (NPB - 1);
        int l0 = (slot & 15) * TL;
        int m0 = (slot >> 4) * TM;

        // ---- token prep: features, zero atok, shuffle-scan, scatter ----
        int n = npt[b * NTOK + tid];
        {
            int v = n;
            #pragma unroll
            for (int o = 1; o < 64; o <<= 1) {
                int u = __shfl_up(v, o, 64);
                if (lane >= o) v += u;
            }
            if (lane == 63) s->wsum[wv] = v;
            float pd = is_d[b * NTOK + tid], pr = is_r[b * NTOK + tid];
            float pp = is_p[b * NTOK + tid], pl = is_l[b * NTOK + tid];
            s->isl[tid]  = pl;
            s->poly[tid] = pp + pd + pr;
            s->nuc[tid]  = pd + pr;
            s->tmk[tid]  = tok_mask[b * NTOK + tid];
            #pragma unroll
            for (int i = 0; i < NATOM / NTOK; i++) s->atokp1[tid + i * NTOK] = 0;
            __syncthreads();
            int pref = 0;
            for (int w = 0; w < wv; w++) pref += s->wsum[w];
            int cum = v + pref;
            int end = min(cum, NATOM), start = min(cum - n, NATOM);
            unsigned short tk1 = (unsigned short)(tid + 1);
            for (int i = start; i < end; i++) s->atokp1[i] = tk1;
        }
        __syncthreads();

        const float* Xb = x + (size_t)b * NATOM * 3;
        const float* Gb = gt + (size_t)b * NATOM * 3;
        const float* Mb = gmask + (size_t)b * NATOM;

        // ---- stage tile atoms (no binary search: 1 LDS read) ----
        if (tid < TL) {
            int l = l0 + tid;
            int v = s->atokp1[l];
            int tok = v ? v - 1 : 0;
            float oh = v ? s->tmk[tok] : 0.0f;
            float ml = Mb[l];
            s->lx[tid] = make_float4(Xb[l * 3], Xb[l * 3 + 1], Xb[l * 3 + 2], ml);
            s->lg[tid] = make_float4(Gb[l * 3], Gb[l * 3 + 1], Gb[l * 3 + 2], s->isl[tok] * oh * ml);
            s->lnuc[tid] = s->nuc[tok] * oh;
            s->ltok[tid] = tok;
        } else if (tid < TL + TM) {
            int i = tid - TL, m = m0 + i;
            int v = s->atokp1[m];
            int tok = v ? v - 1 : 0;
            float oh = v ? s->tmk[tok] : 0.0f;
            float mm = Mb[m];
            s->mx[i] = make_float4(Xb[m * 3], Xb[m * 3 + 1], Xb[m * 3 + 2], mm);
            s->mg[i] = make_float4(Gb[m * 3], Gb[m * 3 + 1], Gb[m * 3 + 2], s->poly[tok] * oh * mm);
            s->mtok[i] = tok;
        }
        __syncthreads();
        if (tid == 0) {
            int tl0 = s->ltok[0], tl1 = s->ltok[TL - 1];
            int tm0 = s->mtok[0], tm1 = s->mtok[TM - 1];
            int spanL = tl1 - tl0 + 1, spanM = tm1 - tm0 + 1;
            int stride = spanM | 1;
            int fits = (spanL >= 1) && (spanM >= 1) && (spanL * stride <= TBBUF);
            s->info[0] = fits; s->info[1] = stride; s->info[2] = spanM;
            s->info[3] = tl0; s->info[4] = tm0; s->info[5] = spanL;
        }
        __syncthreads();
        int fits = s->info[0], stride = s->info[1], spanM = s->info[2];
        int tl0 = s->info[3], tm0 = s->info[4], spanL = s->info[5];
        if (tid < TL) {
            int tk = s->ltok[tid];
            s->lrow[tid] = fits ? min(max(tk - tl0, 0), spanL - 1) * stride : tk * NTOK;
        } else if (tid < TL + TM) {
            int tk = s->mtok[tid - TL];
            s->mrel[tid - TL] = fits ? min(max(tk - tm0, 0), spanM - 1) : tk;
        }
        const float* tbg = tb + (size_t)b * NTOK * NTOK;
        if (fits) {
            int cnt = spanL * stride;
            for (int i = tid; i < cnt; i += 256) {
                int r = i / stride, cc = i - r * stride;
                if (cc < spanM) s->tbuf[i] = tbg[(tl0 + r) * NTOK + tm0 + cc];
            }
        }
        __syncthreads();

        // ---- main loop: 4 l-atoms x 8 m-atoms per thread ----
        int lt = tid & 31, mg = tid >> 5;     // mg in [0,8)
        float4 lxv[4], lgv[4]; float lnu[4]; int lrw[4], gli[4];
        #pragma unroll
        for (int k = 0; k < 4; k++) {
            int li = lt + 32 * k;
            lxv[k] = s->lx[li]; lgv[k] = s->lg[li];
            lnu[k] = s->lnuc[li]; lrw[k] = s->lrow[li]; gli[k] = l0 + li;
        }
        float bnum = 0.f, bden = 0.f, ce = 0.f, cs = 0.f;
        const float k1 = 0.60653066f, k2 = 0.36787944f, k3 = 0.13533528f, k4 = 0.018315639f;

        auto body = [&](auto ldtb) {
            int mstart = mg * 8;
            #pragma unroll 2
            for (int j = 0; j < 8; j++) {
                int m = mstart + j;
                float4 mxv = s->mx[m], mgv = s->mg[m];
                int mrel = s->mrel[m];
                int gmi = m0 + m;
                #pragma unroll
                for (int k = 0; k < 4; k++) {
                    float dx0 = lxv[k].x - mxv.x, dx1 = lxv[k].y - mxv.y, dx2 = lxv[k].z - mxv.z;
                    float dg0 = lgv[k].x - mgv.x, dg1 = lgv[k].y - mgv.y, dg2 = lgv[k].z - mgv.z;
                    float dxv = fsqrt_(fmaf(dx2, dx2, fmaf(dx1, dx1, fmaf(dx0, dx0, 1e-12f))));
                    float dgv = fsqrt_(fmaf(dg2, dg2, fmaf(dg1, dg1, fmaf(dg0, dg0, 1e-12f))));
                    float diff = dxv - dgv;
                    float tbv = ldtb(lrw[k], mrel);
                    float bmv = tbv * (lgv[k].w * mgv.w);
                    bden += bmv;
                    bnum = fmaf(diff * diff, bmv, bnum);
                    float d = fabsf(diff);
                    float u = __expf(d);              // sig(a-d) = 1/(1 + e^d * e^-a)
                    float e1 = frcp(fmaf(u, k1, 1.0f));
                    float e2 = frcp(fmaf(u, k2, 1.0f));
                    float e3 = frcp(fmaf(u, k3, 1.0f));
                    float e4 = frcp(fmaf(u, k4, 1.0f));
                    float es = (e1 + e2) + (e3 + e4);
                    float pm = lxv[k].w * mxv.w;
                    float ccv = dgv < 30.0f ? (dgv < 15.0f ? 1.0f : lnu[k]) : 0.0f;
                    float pm2 = (gli[k] != gmi) ? pm : 0.0f;
                    float cm2 = ccv * pm2;
                    cs += cm2;
                    ce = fmaf(cm2 * 0.25f, es, ce);
                }
            }
        };
        if (fits) body([&](int r, int c) -> float { return s->tbuf[r + c]; });
        else      body([&](int r, int c) -> float { return tbg[r + c]; });

        // ---- block reduction -> one float4 store to private ws slot ----
        float vals[4] = {bnum, bden, ce, cs};
        #pragma unroll
        for (int q = 0; q < 4; q++) {
            float v = fred64(vals[q]);
            if (lane == 0) s->pred[wv][q] = v;
        }
        __syncthreads();
        if (tid == 0) {
            float4 o;
            o.x = s->pred[0][0] + s->pred[1][0] + s->pred[2][0] + s->pred[3][0];
            o.y = s->pred[0][1] + s->pred[1][1] + s->pred[2][1] + s->pred[3][1];
            o.z = s->pred[0][2] + s->pred[1][2] + s->pred[2][2] + s->pred[3][2];
            o.w = s->pred[0][3] + s->pred[1][3] + s->pred[2][3] + s->pred[3][3];
            partials4[(size_t)b * NPB + slot] = o;
        }
    } else {
        // ================= align path (one block per batch) =================
        AlignSh* s = (AlignSh*)smem;
        int b = id;

        // ---- token scan + scatter per-atom weight ----
        {
            int n = npt[b * NTOK + tid];
            int v = n;
            #pragma unroll
            for (int o = 1; o < 64; o <<= 1) {
                int u = __shfl_up(v, o, 64);
                if (lane >= o) v += u;
            }
            if (lane == 63) s->wsum[wv] = v;
            #pragma unroll
            for (int i = 0; i < NATOM / NTOK; i++) s->aw[tid + i * NTOK] = 0.0f;
            float pd = is_d[b * NTOK + tid], pr = is_r[b * NTOK + tid];
            float pl = is_l[b * NTOK + tid];
            float wtv = (1.0f + 5.0f * pd + 5.0f * pr + 10.0f * pl) * tok_mask[b * NTOK + tid];
            __syncthreads();
            int pref = 0;
            for (int w = 0; w < wv; w++) pref += s->wsum[w];
            int cum = v + pref;
            int end = min(cum, NATOM), start = min(cum - n, NATOM);
            for (int i = start; i < end; i++) s->aw[i] = wtv;
        }
        __syncthreads();

        const float* X = x + (size_t)b * NATOM * 3;
        const float* G = gt + (size_t)b * NATOM * 3;
        const float* M = gmask + (size_t)b * NATOM;

        // ---- pass 1: 17 raw sums (double, parallel) ----
        double p[17];
        #pragma unroll
        for (int q = 0; q < 17; q++) p[q] = 0.0;
        for (int a = tid; a < NATOM; a += 256) {
            double m = M[a], wm = (double)s->aw[a] * m;
            double x0 = X[a * 3], x1 = X[a * 3 + 1], x2 = X[a * 3 + 2];
            double g0 = G[a * 3], g1 = G[a * 3 + 1], g2 = G[a * 3 + 2];
            p[0] += m; p[1] += wm;
            p[2] += wm * x0; p[3] += wm * x1; p[4] += wm * x2;
            p[5] += wm * g0; p[6] += wm * g1; p[7] += wm * g2;
            p[8]  += wm * x0 * g0; p[9]  += wm * x0 * g1; p[10] += wm * x0 * g2;
            p[11] += wm * x1 * g0; p[12] += wm * x1 * g1; p[13] += wm * x1 * g2;
            p[14] += wm * x2 * g0; p[15] += wm * x2 * g1; p[16] += wm * x2 * g2;
        }
        #pragma unroll
        for (int q = 0; q < 17; q++) {
            double v = wred64(p[q]);
            if (lane == 0) s->dred[wv][q] = v;
        }
        __syncthreads();
        if (tid == 0) {
            double sh[17];
            for (int q = 0; q < 17; q++)
                sh[q] = s->dred[0][q] + s->dred[1][q] + s->dred[2][q] + s->dred[3][q];
            double ms;
            kabsch_from_sums(sh, s->Rf, s->muf, &ms);
            s->msum = ms;
        }
        __syncthreads();

        // ---- pass 2: weighted MSE ----
        float R00 = s->Rf[0], R01 = s->Rf[1], R02 = s->Rf[2];
        float R10 = s->Rf[3], R11 = s->Rf[4], R12 = s->Rf[5];
        float R20 = s->Rf[6], R21 = s->Rf[7], R22 = s->Rf[8];
        float mux0 = s->muf[0], mux1 = s->muf[1], mux2 = s->muf[2];
        float mug0 = s->muf[3], mug1 = s->muf[4], mug2 = s->muf[5];
        double part = 0.0;
        for (int a = tid; a < NATOM; a += 256) {
            float w = s->aw[a], m = M[a];
            float gc0 = G[a * 3] - mug0, gc1 = G[a * 3 + 1] - mug1, gc2 = G[a * 3 + 2] - mug2;
            float al0 = fmaf(R00, gc0, fmaf(R01, gc1, fmaf(R02, gc2, mux0)));
            float al1 = fmaf(R10, gc0, fmaf(R11, gc1, fmaf(R12, gc2, mux1)));
            float al2 = fmaf(R20, gc0, fmaf(R21, gc1, fmaf(R22, gc2, mux2)));
            float r0 = X[a * 3] - al0, r1 = X[a * 3 + 1] - al1, r2 = X[a * 3 + 2] - al2;
            part += (double)(w * m * (r0 * r0 + r1 * r1 + r2 * r2));
        }
        {
            double v = wred64(part);
            if (lane == 0) s->mred[wv] = v;
        }
        __syncthreads();
        if (tid == 0)
            lmse[b] = (float)((s->mred[0] + s->mred[1] + s->mred[2] + s->mred[3]) / (3.0 * s->msum));
    }
}

// ============ final: reduce pair partials + combine ============
__global__ __launch_bounds__(256) void final_kernel(
    const float4* __restrict__ partials4, const float* __restrict__ lmse,
    const float* __restrict__ t, float* __restrict__ out)
{
    int tid = threadIdx.x, lane = tid & 63, wv = tid >> 6;
    double pr[2][4] = {{0, 0, 0, 0}, {0, 0, 0, 0}};
    #pragma unroll
    for (int b = 0; b < BATCH; b++)
        for (int sI = tid; sI < NPB; sI += 256) {
            float4 v = partials4[(size_t)b * NPB + sI];
            pr[b][0] += v.x; pr[b][1] += v.y; pr[b][2] += v.z; pr[b][3] += v.w;
        }
    __shared__ double sred[4][8];
    #pragma unroll
    for (int b = 0; b < BATCH; b++)
        #pragma unroll
        for (int q = 0; q < 4; q++) {
            double v = wred64(pr[b][q]);
            if (lane == 0) sred[wv][b * 4 + q] = v;
        }
    __syncthreads();
    if (tid == 0) {
        double tot = 0.0;
        for (int b = 0; b < BATCH; b++) {
            double bn = 0, bd = 0, ce = 0, cs = 0;
            for (int w = 0; w < 4; w++) {
                bn += sred[w][b * 4 + 0]; bd += sred[w][b * 4 + 1];
                ce += sred[w][b * 4 + 2]; cs += sred[w][b * 4 + 3];
            }
            double l_bond = bn / bd;
            double l_lddt = 1.0 - ce / cs;
            double tt = t[b];
            double w_t = (tt * tt + 256.0) / ((tt + 16.0) * (tt + 16.0));
            tot += w_t * ((double)lmse[b] + l_bond) + l_lddt;
        }
        out[0] = (float)(tot / (double)BATCH);
    }
}

extern "C" void kernel_launch(void* const* d_in, const int* in_sizes, int n_in,
                              void* d_out, int out_size, void* d_ws, size_t ws_size,
                              hipStream_t stream) {
    const float* x     = (const float*)d_in[0];
    const float* gt    = (const float*)d_in[1];
    const float* gmask = (const float*)d_in[2];
    const float* is_p  = (const float*)d_in[3];
    const float* is_d  = (const float*)d_in[4];
    const float* is_r  = (const float*)d_in[5];
    const float* is_l  = (const float*)d_in[6];
    const float* tb    = (const float*)d_in[7];
    const float* tm    = (const float*)d_in[8];
    const int*   npt   = (const int*)d_in[9];
    const float* t     = (const float*)d_in[10];
    float* out = (float*)d_out;

    float4* partials4 = (float4*)d_ws;                                    // [BATCH][NPB]
    float*  lmse      = (float*)((char*)d_ws + (size_t)BATCH * NPB * sizeof(float4));

    pair_align_kernel<<<BATCH + 2 * NPB, 256, 0, stream>>>(
        x, gt, gmask, tb, is_p, is_d, is_r, is_l, tm, npt, partials4, lmse);
    final_kernel<<<1, 256, 0, stream>>>(partials4, lmse, t, out);
}

// Round 6
// 90.552 us; speedup vs baseline: 1.3345x; 1.0648x over previous
//
#include <hip/hip_runtime.h>
#include <math.h>

#define BATCH 2
#define NTOK  256
#define NATOM 2048
#define TS 64                 // square pair tile
#define NT (NATOM / TS)       // 32 tiles per dim
#define NTRI (NT * (NT + 1) / 2)   // 528 upper-tri tiles per batch
#define TBCAP 1156            // per tb sub-tile LDS floats (34x34)

__device__ __forceinline__ float frcp(float x)  { return __builtin_amdgcn_rcpf(x); }
__device__ __forceinline__ float fsqrt_(float x){ return __builtin_amdgcn_sqrtf(x); }

__device__ __forceinline__ double wred64(double v) {
    for (int o = 32; o > 0; o >>= 1) v += __shfl_down(v, o, 64);
    return v;
}
__device__ __forceinline__ float fred64(float v) {
    for (int o = 32; o > 0; o >>= 1) v += __shfl_down(v, o, 64);
    return v;
}

// Kabsch from 17 raw double sums (fp32 internals; R err ~1e-5 ok vs 0.21 threshold).
__device__ void kabsch_from_sums(const double* shd, float* Rf, float* muf, double* masksum) {
    double wmsum = shd[1];
    float H[3][3];
    for (int i = 0; i < 3; i++)
        for (int j = 0; j < 3; j++)
            H[i][j] = (float)(shd[8 + i * 3 + j] - shd[2 + i] * shd[5 + j] / wmsum);
    float A[3][3];
    for (int j = 0; j < 3; j++) for (int k = 0; k < 3; k++) {
        float s = 0.f; for (int i = 0; i < 3; i++) s = fmaf(H[i][j], H[i][k], s);
        A[j][k] = s;
    }
    float V[3][3] = {{1, 0, 0}, {0, 1, 0}, {0, 0, 1}};
    for (int sweep = 0; sweep < 6; ++sweep) {
        float off = fabsf(A[0][1]) + fabsf(A[0][2]) + fabsf(A[1][2]);
        float diag = fabsf(A[0][0]) + fabsf(A[1][1]) + fabsf(A[2][2]);
        if (off < 1e-7f * diag) break;
        for (int pi = 0; pi < 3; ++pi) {
            int pp_ = (pi == 2) ? 1 : 0;
            int qq_ = (pi == 0) ? 1 : 2;
            float apq = A[pp_][qq_];
            float sc = fabsf(A[pp_][pp_]) + fabsf(A[qq_][qq_]);
            if (fabsf(apq) <= 1e-9f * sc) continue;
            float theta = (A[qq_][qq_] - A[pp_][pp_]) * 0.5f * frcp(apq);
            float t_ = ((theta >= 0.f) ? 1.0f : -1.0f) * frcp(fabsf(theta) + fsqrt_(fmaf(theta, theta, 1.0f)));
            float c_ = frcp(fsqrt_(fmaf(t_, t_, 1.0f))), sn = t_ * c_;
            for (int k = 0; k < 3; k++) { float akp = A[k][pp_], akq = A[k][qq_];
                A[k][pp_] = c_ * akp - sn * akq; A[k][qq_] = sn * akp + c_ * akq; }
            for (int k = 0; k < 3; k++) { float apk = A[pp_][k], aqk = A[qq_][k];
                A[pp_][k] = c_ * apk - sn * aqk; A[qq_][k] = sn * apk + c_ * aqk; }
            for (int k = 0; k < 3; k++) { float vkp = V[k][pp_], vkq = V[k][qq_];
                V[k][pp_] = c_ * vkp - sn * vkq; V[k][qq_] = sn * vkp + c_ * vkq; }
        }
    }
    float lam[3] = {A[0][0], A[1][1], A[2][2]};
    int idx[3] = {0, 1, 2};
    for (int i = 0; i < 2; i++) for (int j = i + 1; j < 3; j++)
        if (lam[idx[j]] > lam[idx[i]]) { int tsw = idx[i]; idx[i] = idx[j]; idx[j] = tsw; }
    float Vs[3][3], sv[3];
    for (int k = 0; k < 3; k++) {
        sv[k] = fsqrt_(fmaxf(lam[idx[k]], 0.0f));
        for (int i = 0; i < 3; i++) Vs[i][k] = V[i][idx[k]];
    }
    float U[3][3] = {{1, 0, 0}, {0, 1, 0}, {0, 0, 1}};
    for (int k = 0; k < 3; k++) {
        if (sv[k] > 1e-6f * sv[0] + 1e-30f) {
            float inv = frcp(sv[k]);
            for (int i = 0; i < 3; i++) {
                float s = 0.f; for (int j = 0; j < 3; j++) s = fmaf(H[i][j], Vs[j][k], s);
                U[i][k] = s * inv;
            }
        } else if (k == 2) {
            U[0][2] = U[1][0] * U[2][1] - U[2][0] * U[1][1];
            U[1][2] = U[2][0] * U[0][1] - U[0][0] * U[2][1];
            U[2][2] = U[0][0] * U[1][1] - U[1][0] * U[0][1];
        }
    }
    float R0[3][3];
    for (int i = 0; i < 3; i++) for (int j = 0; j < 3; j++) {
        float s = 0.f; for (int k = 0; k < 3; k++) s = fmaf(U[i][k], Vs[j][k], s);
        R0[i][j] = s;
    }
    float det = R0[0][0] * (R0[1][1] * R0[2][2] - R0[1][2] * R0[2][1])
              - R0[0][1] * (R0[1][0] * R0[2][2] - R0[1][2] * R0[2][0])
              + R0[0][2] * (R0[1][0] * R0[2][1] - R0[1][1] * R0[2][0]);
    float s2 = (det < 0.0f) ? -1.0f : 1.0f;
    for (int i = 0; i < 3; i++) for (int j = 0; j < 3; j++)
        Rf[i * 3 + j] = fmaf(U[i][0], Vs[j][0], fmaf(U[i][1], Vs[j][1], s2 * U[i][2] * Vs[j][2]));
    for (int i = 0; i < 3; i++) {
        muf[i]     = (float)(shd[2 + i] / wmsum);
        muf[3 + i] = (float)(shd[5 + i] / wmsum);
    }
    *masksum = shd[0];
}

struct PairSh {
    float  isl[NTOK], poly[NTOK], nuc[NTOK], tmk[NTOK];
    int    wsum[4];
    unsigned short atokp1[NATOM];   // token+1, 0 = invalid atom
    float4 ax[2 * TS], ag[2 * TS];  // [0,TS)=l-side, [TS,2TS)=m-side; ax.w=mask, ag.w=nuc*oh
    float2 af[2 * TS];              // (isl*oh, poly*oh)
    int    rel[2 * TS];             // token idx: relative (fits) or absolute
    float  tbA[TBCAP], tbB[TBCAP];  // tb[l-span][m-span], tb[m-span][l-span]
    int    info[5];
    float  pred[4][4];
};
struct AlignSh {
    int    wsum[4];
    float  aw[NATOM];
    double dred[4][17];
    float  Rf[9], muf[6];
    double msum;
    double mred[4];
};

// ===== fused: 2 align blocks (ids 0,1) + 2*528 upper-tri pair tiles =====
__global__ __launch_bounds__(256) void pair_align_kernel(
    const float* __restrict__ x, const float* __restrict__ gt,
    const float* __restrict__ gmask, const float* __restrict__ tb,
    const float* __restrict__ is_p, const float* __restrict__ is_d,
    const float* __restrict__ is_r, const float* __restrict__ is_l,
    const float* __restrict__ tok_mask, const int* __restrict__ npt,
    float4* __restrict__ partials4, float* __restrict__ lmse)
{
    __shared__ __align__(16) char smem[sizeof(PairSh) > sizeof(AlignSh) ? sizeof(PairSh) : sizeof(AlignSh)];
    int id = blockIdx.x;
    int tid = threadIdx.x;
    int lane = tid & 63, wvi = tid >> 6;

    if (id >= BATCH) {
        // ================= pair path (upper-tri 64x64 tiles) =================
        PairSh* s = (PairSh*)smem;
        int pid = id - BATCH;
        int b = (pid >= NTRI) ? 1 : 0;
        int tri = pid - b * NTRI;
        int ti = 0, off = 0;
        while (off + (NT - ti) <= tri) { off += NT - ti; ti++; }
        int tj = ti + (tri - off);
        int l0 = ti * TS, m0 = tj * TS;
        int diag = (ti == tj);

        // ---- token prep: features, zero atok, shuffle-scan, scatter ----
        int n = npt[b * NTOK + tid];
        {
            int v = n;
            #pragma unroll
            for (int o = 1; o < 64; o <<= 1) {
                int u = __shfl_up(v, o, 64);
                if (lane >= o) v += u;
            }
            if (lane == 63) s->wsum[wvi] = v;
            float pd = is_d[b * NTOK + tid], pr = is_r[b * NTOK + tid];
            float pp = is_p[b * NTOK + tid], pl = is_l[b * NTOK + tid];
            s->isl[tid]  = pl;
            s->poly[tid] = pp + pd + pr;
            s->nuc[tid]  = pd + pr;
            s->tmk[tid]  = tok_mask[b * NTOK + tid];
            #pragma unroll
            for (int i = 0; i < NATOM / NTOK; i++) s->atokp1[tid + i * NTOK] = 0;
            __syncthreads();
            int pref = 0;
            for (int w = 0; w < wvi; w++) pref += s->wsum[w];
            int cum = v + pref;
            int end = min(cum, NATOM), start = min(cum - n, NATOM);
            unsigned short tk1 = (unsigned short)(tid + 1);
            for (int i = start; i < end; i++) s->atokp1[i] = tk1;
        }
        __syncthreads();

        const float* Xb = x + (size_t)b * NATOM * 3;
        const float* Gb = gt + (size_t)b * NATOM * 3;
        const float* Mb = gmask + (size_t)b * NATOM;

        // ---- span info ----
        if (tid == 0) {
            int v0 = s->atokp1[l0], v1 = s->atokp1[l0 + TS - 1];
            int w0 = s->atokp1[m0], w1 = s->atokp1[m0 + TS - 1];
            int tl0 = v0 ? v0 - 1 : 0, tl1 = v1 ? v1 - 1 : 0;
            int tm0 = w0 ? w0 - 1 : 0, tm1 = w1 ? w1 - 1 : 0;
            int spanL = tl1 - tl0 + 1, spanM = tm1 - tm0 + 1;
            int sA = spanM | 1, sB = spanL | 1;
            int fits = (spanL * sA <= TBCAP) && (spanM * sB <= TBCAP);
            s->info[0] = fits; s->info[1] = sA; s->info[2] = sB;
            s->info[3] = tl0; s->info[4] = tm0;
            // reuse pred[0] row to pass spans
            ((int*)s->pred)[0] = spanL; ((int*)s->pred)[1] = spanM;
        }
        __syncthreads();
        int fits = s->info[0], sA = s->info[1], sB = s->info[2];
        int tl0 = s->info[3], tm0 = s->info[4];
        int spanL = ((int*)s->pred)[0], spanM = ((int*)s->pred)[1];

        // ---- stage atoms (tid<128: one atom each) ----
        if (tid < 2 * TS) {
            int side = tid >> 6, idx = tid & (TS - 1);
            int a = (side ? m0 : l0) + idx;
            int v = s->atokp1[a];
            int tok = v ? v - 1 : 0;
            float oh = v ? s->tmk[tok] : 0.0f;
            float mk = Mb[a];
            s->ax[tid] = make_float4(Xb[a * 3], Xb[a * 3 + 1], Xb[a * 3 + 2], mk);
            s->ag[tid] = make_float4(Gb[a * 3], Gb[a * 3 + 1], Gb[a * 3 + 2], s->nuc[tok] * oh);
            s->af[tid] = make_float2(s->isl[tok] * oh, s->poly[tok] * oh);
            int base = side ? tm0 : tl0;
            int span = side ? spanM : spanL;
            s->rel[tid] = fits ? min(max(tok - base, 0), span - 1) : tok;
        }
        const float* tbg = tb + (size_t)b * NTOK * NTOK;
        if (fits) {
            int cntA = spanL * sA;
            for (int i = tid; i < cntA; i += 256) {
                int r = i / sA, cc = i - r * sA;
                if (cc < spanM) s->tbA[i] = tbg[(tl0 + r) * NTOK + tm0 + cc];
            }
            int cntB = spanM * sB;
            for (int i = tid; i < cntB; i += 256) {
                int r = i / sB, cc = i - r * sB;
                if (cc < spanL) s->tbB[i] = tbg[(tm0 + r) * NTOK + tl0 + cc];
            }
        }
        __syncthreads();

        // ---- per-thread l regs: 4 l-atoms, 4 m's per group (16 groups) ----
        int lt = tid & 15, mg = tid >> 4;
        float4 lx4[4], lg4[4]; float2 lf2[4]; int lrel[4], gl[4];
        #pragma unroll
        for (int k = 0; k < 4; k++) {
            int li = lt + 16 * k;
            lx4[k] = s->ax[li]; lg4[k] = s->ag[li]; lf2[k] = s->af[li];
            lrel[k] = s->rel[li]; gl[k] = l0 + li;
        }
        float bnum = 0.f, bden = 0.f, ce = 0.f, cs = 0.f;
        const float k1 = 0.60653066f, k2 = 0.36787944f, k3 = 0.13533528f, k4 = 0.018315639f;

        auto run = [&](auto ldA, auto ldB) {
            int mstart = mg * 4;
            if (diag) {
                #pragma unroll 2
                for (int j = 0; j < 4; j++) {
                    int m = mstart + j;
                    float4 mx4 = s->ax[TS + m], mg4 = s->ag[TS + m];
                    float2 mf = s->af[TS + m];
                    int mr = s->rel[TS + m];
                    int gm = m0 + m;
                    #pragma unroll
                    for (int k = 0; k < 4; k++) {
                        float dx0 = lx4[k].x - mx4.x, dx1 = lx4[k].y - mx4.y, dx2 = lx4[k].z - mx4.z;
                        float dg0 = lg4[k].x - mg4.x, dg1 = lg4[k].y - mg4.y, dg2 = lg4[k].z - mg4.z;
                        float dxv = fsqrt_(fmaf(dx2, dx2, fmaf(dx1, dx1, fmaf(dx0, dx0, 1e-12f))));
                        float dgv = fsqrt_(fmaf(dg2, dg2, fmaf(dg1, dg1, fmaf(dg0, dg0, 1e-12f))));
                        float diff = dxv - dgv;
                        float tbv = ldA(lrel[k], mr);
                        float pm = lx4[k].w * mx4.w;
                        float bmv = tbv * lf2[k].x * mf.y * pm;
                        bden += bmv;
                        bnum = fmaf(diff * diff, bmv, bnum);
                        float d = fabsf(diff);
                        float u = __expf(d);
                        float e1 = frcp(fmaf(u, k1, 1.0f));
                        float e2 = frcp(fmaf(u, k2, 1.0f));
                        float e3 = frcp(fmaf(u, k3, 1.0f));
                        float e4 = frcp(fmaf(u, k4, 1.0f));
                        float es = (e1 + e2) + (e3 + e4);
                        float nl = lg4[k].w;
                        float ccv = dgv < 30.0f ? (dgv < 15.0f ? 1.0f : nl) : 0.0f;
                        float pm2 = (gl[k] != gm) ? pm : 0.0f;
                        float cm2 = ccv * pm2;
                        cs += cm2;
                        ce = fmaf(cm2 * 0.25f, es, ce);
                    }
                }
            } else {
                #pragma unroll 2
                for (int j = 0; j < 4; j++) {
                    int m = mstart + j;
                    float4 mx4 = s->ax[TS + m], mg4 = s->ag[TS + m];
                    float2 mf = s->af[TS + m];
                    int mr = s->rel[TS + m];
                    #pragma unroll
                    for (int k = 0; k < 4; k++) {
                        float dx0 = lx4[k].x - mx4.x, dx1 = lx4[k].y - mx4.y, dx2 = lx4[k].z - mx4.z;
                        float dg0 = lg4[k].x - mg4.x, dg1 = lg4[k].y - mg4.y, dg2 = lg4[k].z - mg4.z;
                        float dxv = fsqrt_(fmaf(dx2, dx2, fmaf(dx1, dx1, fmaf(dx0, dx0, 1e-12f))));
                        float dgv = fsqrt_(fmaf(dg2, dg2, fmaf(dg1, dg1, fmaf(dg0, dg0, 1e-12f))));
                        float diff = dxv - dgv;
                        float pm = lx4[k].w * mx4.w;
                        // bond, both orientations
                        float tb1 = ldA(lrel[k], mr);
                        float tb2 = ldB(mr, lrel[k]);
                        float bsum = (tb1 * lf2[k].x * mf.y + tb2 * mf.x * lf2[k].y) * pm;
                        bden += bsum;
                        bnum = fmaf(diff * diff, bsum, bnum);
                        // lddt, both orientations: c_l + c_m
                        float d = fabsf(diff);
                        float u = __expf(d);
                        float e1 = frcp(fmaf(u, k1, 1.0f));
                        float e2 = frcp(fmaf(u, k2, 1.0f));
                        float e3 = frcp(fmaf(u, k3, 1.0f));
                        float e4 = frcp(fmaf(u, k4, 1.0f));
                        float es = (e1 + e2) + (e3 + e4);
                        float sn = lg4[k].w + mg4.w;
                        float ccv = (dgv < 30.0f ? sn : 0.0f) + (dgv < 15.0f ? (2.0f - sn) : 0.0f);
                        float cm2 = ccv * pm;
                        cs += cm2;
                        ce = fmaf(cm2 * 0.25f, es, ce);
                    }
                }
            }
        };
        if (fits) run([&](int r, int c) -> float { return s->tbA[r * sA + c]; },
                      [&](int r, int c) -> float { return s->tbB[r * sB + c]; });
        else      run([&](int r, int c) -> float { return tbg[r * NTOK + c]; },
                      [&](int r, int c) -> float { return tbg[r * NTOK + c]; });

        // ---- block reduction -> one float4 store ----
        float vals[4] = {bnum, bden, ce, cs};
        #pragma unroll
        for (int q = 0; q < 4; q++) {
            float v = fred64(vals[q]);
            if (lane == 0) s->pred[wvi][q] = v;
        }
        __syncthreads();
        if (tid == 0) {
            float4 o;
            o.x = s->pred[0][0] + s->pred[1][0] + s->pred[2][0] + s->pred[3][0];
            o.y = s->pred[0][1] + s->pred[1][1] + s->pred[2][1] + s->pred[3][1];
            o.z = s->pred[0][2] + s->pred[1][2] + s->pred[2][2] + s->pred[3][2];
            o.w = s->pred[0][3] + s->pred[1][3] + s->pred[2][3] + s->pred[3][3];
            partials4[(size_t)b * NTRI + tri] = o;
        }
    } else {
        // ================= align path (one block per batch) =================
        AlignSh* s = (AlignSh*)smem;
        int b = id;

        {
            int n = npt[b * NTOK + tid];
            int v = n;
            #pragma unroll
            for (int o = 1; o < 64; o <<= 1) {
                int u = __shfl_up(v, o, 64);
                if (lane >= o) v += u;
            }
            if (lane == 63) s->wsum[wvi] = v;
            #pragma unroll
            for (int i = 0; i < NATOM / NTOK; i++) s->aw[tid + i * NTOK] = 0.0f;
            float pd = is_d[b * NTOK + tid], pr = is_r[b * NTOK + tid];
            float pl = is_l[b * NTOK + tid];
            float wtv = (1.0f + 5.0f * pd + 5.0f * pr + 10.0f * pl) * tok_mask[b * NTOK + tid];
            __syncthreads();
            int pref = 0;
            for (int w = 0; w < wvi; w++) pref += s->wsum[w];
            int cum = v + pref;
            int end = min(cum, NATOM), start = min(cum - n, NATOM);
            for (int i = start; i < end; i++) s->aw[i] = wtv;
        }
        __syncthreads();

        const float* X = x + (size_t)b * NATOM * 3;
        const float* G = gt + (size_t)b * NATOM * 3;
        const float* M = gmask + (size_t)b * NATOM;

        double p[17];
        #pragma unroll
        for (int q = 0; q < 17; q++) p[q] = 0.0;
        for (int a = tid; a < NATOM; a += 256) {
            double m = M[a], wm = (double)s->aw[a] * m;
            double x0 = X[a * 3], x1 = X[a * 3 + 1], x2 = X[a * 3 + 2];
            double g0 = G[a * 3], g1 = G[a * 3 + 1], g2 = G[a * 3 + 2];
            p[0] += m; p[1] += wm;
            p[2] += wm * x0; p[3] += wm * x1; p[4] += wm * x2;
            p[5] += wm * g0; p[6] += wm * g1; p[7] += wm * g2;
            p[8]  += wm * x0 * g0; p[9]  += wm * x0 * g1; p[10] += wm * x0 * g2;
            p[11] += wm * x1 * g0; p[12] += wm * x1 * g1; p[13] += wm * x1 * g2;
            p[14] += wm * x2 * g0; p[15] += wm * x2 * g1; p[16] += wm * x2 * g2;
        }
        #pragma unroll
        for (int q = 0; q < 17; q++) {
            double v = wred64(p[q]);
            if (lane == 0) s->dred[wvi][q] = v;
        }
        __syncthreads();
        if (tid == 0) {
            double sh[17];
            for (int q = 0; q < 17; q++)
                sh[q] = s->dred[0][q] + s->dred[1][q] + s->dred[2][q] + s->dred[3][q];
            double ms;
            kabsch_from_sums(sh, s->Rf, s->muf, &ms);
            s->msum = ms;
        }
        __syncthreads();

        float R00 = s->Rf[0], R01 = s->Rf[1], R02 = s->Rf[2];
        float R10 = s->Rf[3], R11 = s->Rf[4], R12 = s->Rf[5];
        float R20 = s->Rf[6], R21 = s->Rf[7], R22 = s->Rf[8];
        float mux0 = s->muf[0], mux1 = s->muf[1], mux2 = s->muf[2];
        float mug0 = s->muf[3], mug1 = s->muf[4], mug2 = s->muf[5];
        double part = 0.0;
        for (int a = tid; a < NATOM; a += 256) {
            float w = s->aw[a], m = M[a];
            float gc0 = G[a * 3] - mug0, gc1 = G[a * 3 + 1] - mug1, gc2 = G[a * 3 + 2] - mug2;
            float al0 = fmaf(R00, gc0, fmaf(R01, gc1, fmaf(R02, gc2, mux0)));
            float al1 = fmaf(R10, gc0, fmaf(R11, gc1, fmaf(R12, gc2, mux1)));
            float al2 = fmaf(R20, gc0, fmaf(R21, gc1, fmaf(R22, gc2, mux2)));
            float r0 = X[a * 3] - al0, r1 = X[a * 3 + 1] - al1, r2 = X[a * 3 + 2] - al2;
            part += (double)(w * m * (r0 * r0 + r1 * r1 + r2 * r2));
        }
        {
            double v = wred64(part);
            if (lane == 0) s->mred[wvi] = v;
        }
        __syncthreads();
        if (tid == 0)
            lmse[b] = (float)((s->mred[0] + s->mred[1] + s->mred[2] + s->mred[3]) / (3.0 * s->msum));
    }
}

// ============ final: reduce pair partials + combine ============
__global__ __launch_bounds__(256) void final_kernel(
    const float4* __restrict__ partials4, const float* __restrict__ lmse,
    const float* __restrict__ t, float* __restrict__ out)
{
    int tid = threadIdx.x, lane = tid & 63, wv = tid >> 6;
    double pr[2][4] = {{0, 0, 0, 0}, {0, 0, 0, 0}};
    #pragma unroll
    for (int b = 0; b < BATCH; b++)
        for (int sI = tid; sI < NTRI; sI += 256) {
            float4 v = partials4[(size_t)b * NTRI + sI];
            pr[b][0] += v.x; pr[b][1] += v.y; pr[b][2] += v.z; pr[b][3] += v.w;
        }
    __shared__ double sred[4][8];
    #pragma unroll
    for (int b = 0; b < BATCH; b++)
        #pragma unroll
        for (int q = 0; q < 4; q++) {
            double v = wred64(pr[b][q]);
            if (lane == 0) sred[wv][b * 4 + q] = v;
        }
    __syncthreads();
    if (tid == 0) {
        double tot = 0.0;
        for (int b = 0; b < BATCH; b++) {
            double bn = 0, bd = 0, ce = 0, cs = 0;
            for (int w = 0; w < 4; w++) {
                bn += sred[w][b * 4 + 0]; bd += sred[w][b * 4 + 1];
                ce += sred[w][b * 4 + 2]; cs += sred[w][b * 4 + 3];
            }
            double l_bond = bn / bd;
            double l_lddt = 1.0 - ce / cs;
            double tt = t[b];
            double w_t = (tt * tt + 256.0) / ((tt + 16.0) * (tt + 16.0));
            tot += w_t * ((double)lmse[b] + l_bond) + l_lddt;
        }
        out[0] = (float)(tot / (double)BATCH);
    }
}

extern "C" void kernel_launch(void* const* d_in, const int* in_sizes, int n_in,
                              void* d_out, int out_size, void* d_ws, size_t ws_size,
                              hipStream_t stream) {
    const float* x     = (const float*)d_in[0];
    const float* gt    = (const float*)d_in[1];
    const float* gmask = (const float*)d_in[2];
    const float* is_p  = (const float*)d_in[3];
    const float* is_d  = (const float*)d_in[4];
    const float* is_r  = (const float*)d_in[5];
    const float* is_l  = (const float*)d_in[6];
    const float* tb    = (const float*)d_in[7];
    const float* tm    = (const float*)d_in[8];
    const int*   npt   = (const int*)d_in[9];
    const float* t     = (const float*)d_in[10];
    float* out = (float*)d_out;

    float4* partials4 = (float4*)d_ws;                                    // [BATCH][NTRI]
    float*  lmse      = (float*)((char*)d_ws + (size_t)BATCH * NTRI * sizeof(float4));

    pair_align_kernel<<<BATCH + BATCH * NTRI, 256, 0, stream>>>(
        x, gt, gmask, tb, is_p, is_d, is_r, is_l, tm, npt, partials4, lmse);
    final_kernel<<<1, 256, 0, stream>>>(partials4, lmse, t, out);
}

// Round 7
// 89.747 us; speedup vs baseline: 1.3465x; 1.0090x over previous
//
#include <hip/hip_runtime.h>
#include <math.h>

#define BATCH 2
#define NTOK  256
#define NATOM 2048
#define TS 64                 // square pair tile
#define NT (NATOM / TS)       // 32 tiles per dim
#define NTRI (NT * (NT + 1) / 2)   // 528 tri tiles per batch (32 diag first, then 496)
#define TBCAP 1156            // per tb sub-tile LDS floats (34x34)

__device__ __forceinline__ float frcp(float x)  { return __builtin_amdgcn_rcpf(x); }
__device__ __forceinline__ float fsqrt_(float x){ return __builtin_amdgcn_sqrtf(x); }

__device__ __forceinline__ double wred64(double v) {
    for (int o = 32; o > 0; o >>= 1) v += __shfl_down(v, o, 64);
    return v;
}
__device__ __forceinline__ float fred64(float v) {
    for (int o = 32; o > 0; o >>= 1) v += __shfl_down(v, o, 64);
    return v;
}

// one-rcp smooth-LDDT kernel: es = sum_i 1/(1+u*ki), u = e^d (d clamped <= 20
// so P12*P34 <= ~3e31 stays in fp32 range; tail error ~1e-8, negligible)
__device__ __forceinline__ float lddt_es(float d) {
    const float k1 = 0.60653066f, k2 = 0.36787944f, k3 = 0.13533528f, k4 = 0.018315639f;
    float u = __expf(fminf(d, 20.0f));
    float a1 = fmaf(u, k1, 1.0f), a2 = fmaf(u, k2, 1.0f);
    float a3 = fmaf(u, k3, 1.0f), a4 = fmaf(u, k4, 1.0f);
    float P12 = a1 * a2, P34 = a3 * a4;
    float s12 = a1 + a2, s34 = a3 + a4;
    float num = fmaf(s12, P34, s34 * P12);
    return num * frcp(P12 * P34);
}

// Kabsch from 17 raw double sums (fp32 internals; R err ~1e-5 ok vs 0.21 threshold).
__device__ void kabsch_from_sums(const double* shd, float* Rf, float* muf, double* masksum) {
    double wmsum = shd[1];
    float H[3][3];
    for (int i = 0; i < 3; i++)
        for (int j = 0; j < 3; j++)
            H[i][j] = (float)(shd[8 + i * 3 + j] - shd[2 + i] * shd[5 + j] / wmsum);
    float A[3][3];
    for (int j = 0; j < 3; j++) for (int k = 0; k < 3; k++) {
        float s = 0.f; for (int i = 0; i < 3; i++) s = fmaf(H[i][j], H[i][k], s);
        A[j][k] = s;
    }
    float V[3][3] = {{1, 0, 0}, {0, 1, 0}, {0, 0, 1}};
    for (int sweep = 0; sweep < 6; ++sweep) {
        float off = fabsf(A[0][1]) + fabsf(A[0][2]) + fabsf(A[1][2]);
        float diag = fabsf(A[0][0]) + fabsf(A[1][1]) + fabsf(A[2][2]);
        if (off < 1e-7f * diag) break;
        for (int pi = 0; pi < 3; ++pi) {
            int pp_ = (pi == 2) ? 1 : 0;
            int qq_ = (pi == 0) ? 1 : 2;
            float apq = A[pp_][qq_];
            float sc = fabsf(A[pp_][pp_]) + fabsf(A[qq_][qq_]);
            if (fabsf(apq) <= 1e-9f * sc) continue;
            float theta = (A[qq_][qq_] - A[pp_][pp_]) * 0.5f * frcp(apq);
            float t_ = ((theta >= 0.f) ? 1.0f : -1.0f) * frcp(fabsf(theta) + fsqrt_(fmaf(theta, theta, 1.0f)));
            float c_ = frcp(fsqrt_(fmaf(t_, t_, 1.0f))), sn = t_ * c_;
            for (int k = 0; k < 3; k++) { float akp = A[k][pp_], akq = A[k][qq_];
                A[k][pp_] = c_ * akp - sn * akq; A[k][qq_] = sn * akp + c_ * akq; }
            for (int k = 0; k < 3; k++) { float apk = A[pp_][k], aqk = A[qq_][k];
                A[pp_][k] = c_ * apk - sn * aqk; A[qq_][k] = sn * apk + c_ * aqk; }
            for (int k = 0; k < 3; k++) { float vkp = V[k][pp_], vkq = V[k][qq_];
                V[k][pp_] = c_ * vkp - sn * vkq; V[k][qq_] = sn * vkp + c_ * vkq; }
        }
    }
    float lam[3] = {A[0][0], A[1][1], A[2][2]};
    int idx[3] = {0, 1, 2};
    for (int i = 0; i < 2; i++) for (int j = i + 1; j < 3; j++)
        if (lam[idx[j]] > lam[idx[i]]) { int tsw = idx[i]; idx[i] = idx[j]; idx[j] = tsw; }
    float Vs[3][3], sv[3];
    for (int k = 0; k < 3; k++) {
        sv[k] = fsqrt_(fmaxf(lam[idx[k]], 0.0f));
        for (int i = 0; i < 3; i++) Vs[i][k] = V[i][idx[k]];
    }
    float U[3][3] = {{1, 0, 0}, {0, 1, 0}, {0, 0, 1}};
    for (int k = 0; k < 3; k++) {
        if (sv[k] > 1e-6f * sv[0] + 1e-30f) {
            float inv = frcp(sv[k]);
            for (int i = 0; i < 3; i++) {
                float s = 0.f; for (int j = 0; j < 3; j++) s = fmaf(H[i][j], Vs[j][k], s);
                U[i][k] = s * inv;
            }
        } else if (k == 2) {
            U[0][2] = U[1][0] * U[2][1] - U[2][0] * U[1][1];
            U[1][2] = U[2][0] * U[0][1] - U[0][0] * U[2][1];
            U[2][2] = U[0][0] * U[1][1] - U[1][0] * U[0][1];
        }
    }
    float R0[3][3];
    for (int i = 0; i < 3; i++) for (int j = 0; j < 3; j++) {
        float s = 0.f; for (int k = 0; k < 3; k++) s = fmaf(U[i][k], Vs[j][k], s);
        R0[i][j] = s;
    }
    float det = R0[0][0] * (R0[1][1] * R0[2][2] - R0[1][2] * R0[2][1])
              - R0[0][1] * (R0[1][0] * R0[2][2] - R0[1][2] * R0[2][0])
              + R0[0][2] * (R0[1][0] * R0[2][1] - R0[1][1] * R0[2][0]);
    float s2 = (det < 0.0f) ? -1.0f : 1.0f;
    for (int i = 0; i < 3; i++) for (int j = 0; j < 3; j++)
        Rf[i * 3 + j] = fmaf(U[i][0], Vs[j][0], fmaf(U[i][1], Vs[j][1], s2 * U[i][2] * Vs[j][2]));
    for (int i = 0; i < 3; i++) {
        muf[i]     = (float)(shd[2 + i] / wmsum);
        muf[3 + i] = (float)(shd[5 + i] / wmsum);
    }
    *masksum = shd[0];
}

struct PairSh {
    float  isl[NTOK], poly[NTOK], nuc[NTOK], tmk[NTOK];
    int    wsum[4];
    unsigned short atokp1[NATOM];   // token+1, 0 = invalid atom
    float4 ax[2 * TS], ag[2 * TS];  // [0,TS)=l-side, [TS,2TS)=m-side; ax.w=mask, ag.w=nuc*oh
    float2 af[2 * TS];              // (isl*oh, poly*oh)
    int    rel[2 * TS];             // token idx: relative (fits) or absolute
    float  tbA[TBCAP], tbB[TBCAP];  // tb[l-span][m-span], tb[m-span][l-span]
    int    info[5];
    float  pred[4][4];
};
struct AlignSh {
    int    wsum[4];
    float  aw[NATOM];
    double dred[4][17];
    float  Rf[9], muf[6];
    double msum;
    double mred[4];
};

// ===== fused: 2 align blocks (ids 0,1) + 2*528 tri pair tiles (diag first) =====
__global__ __launch_bounds__(256) void pair_align_kernel(
    const float* __restrict__ x, const float* __restrict__ gt,
    const float* __restrict__ gmask, const float* __restrict__ tb,
    const float* __restrict__ is_p, const float* __restrict__ is_d,
    const float* __restrict__ is_r, const float* __restrict__ is_l,
    const float* __restrict__ tok_mask, const int* __restrict__ npt,
    float4* __restrict__ partials4, float* __restrict__ lmse)
{
    __shared__ __align__(16) char smem[sizeof(PairSh) > sizeof(AlignSh) ? sizeof(PairSh) : sizeof(AlignSh)];
    int id = blockIdx.x;
    int tid = threadIdx.x;
    int lane = tid & 63, wvi = tid >> 6;

    if (id >= BATCH) {
        // ================= pair path (tri 64x64 tiles, diag tiles first) =================
        PairSh* s = (PairSh*)smem;
        int pid = id - BATCH;
        int b = (pid >= NTRI) ? 1 : 0;
        int tri = pid - b * NTRI;
        int ti, tj;
        if (tri < NT) { ti = tj = tri; }                 // 32 diag tiles dispatched first (2x work)
        else {
            int r = tri - NT;                            // strict upper triangle, row-major
            ti = 0; int off = 0;
            while (off + (NT - 1 - ti) <= r) { off += NT - 1 - ti; ti++; }
            tj = ti + 1 + (r - off);
        }
        int l0 = ti * TS, m0 = tj * TS;
        int diag = (ti == tj);

        // ---- token prep: features, shuffle-scan, scatter + tail-zero ----
        int n = npt[b * NTOK + tid];
        {
            int v = n;
            #pragma unroll
            for (int o = 1; o < 64; o <<= 1) {
                int u = __shfl_up(v, o, 64);
                if (lane >= o) v += u;
            }
            if (lane == 63) s->wsum[wvi] = v;
            float pd = is_d[b * NTOK + tid], pr = is_r[b * NTOK + tid];
            float pp = is_p[b * NTOK + tid], pl = is_l[b * NTOK + tid];
            s->isl[tid]  = pl;
            s->poly[tid] = pp + pd + pr;
            s->nuc[tid]  = pd + pr;
            s->tmk[tid]  = tok_mask[b * NTOK + tid];
            __syncthreads();
            int pref = 0;
            for (int w = 0; w < wvi; w++) pref += s->wsum[w];
            int total_ = s->wsum[0] + s->wsum[1] + s->wsum[2] + s->wsum[3];
            int cum = v + pref;
            int end = min(cum, NATOM), start = min(cum - n, NATOM);
            unsigned short tk1 = (unsigned short)(tid + 1);
            for (int i = start; i < end; i++) s->atokp1[i] = tk1;
            for (int i = total_ + tid; i < NATOM; i += 256) s->atokp1[i] = 0;  // tail only
        }
        __syncthreads();

        const float* Xb = x + (size_t)b * NATOM * 3;
        const float* Gb = gt + (size_t)b * NATOM * 3;
        const float* Mb = gmask + (size_t)b * NATOM;

        // ---- span info ----
        if (tid == 0) {
            int v0 = s->atokp1[l0], v1 = s->atokp1[l0 + TS - 1];
            int w0 = s->atokp1[m0], w1 = s->atokp1[m0 + TS - 1];
            int tl0 = v0 ? v0 - 1 : 0, tl1 = v1 ? v1 - 1 : 0;
            int tm0 = w0 ? w0 - 1 : 0, tm1 = w1 ? w1 - 1 : 0;
            int spanL = tl1 - tl0 + 1, spanM = tm1 - tm0 + 1;
            int sA = spanM | 1, sB = spanL | 1;
            int fits = (spanL * sA <= TBCAP) && (spanM * sB <= TBCAP);
            s->info[0] = fits; s->info[1] = sA; s->info[2] = sB;
            s->info[3] = tl0; s->info[4] = tm0;
            ((int*)s->pred)[0] = spanL; ((int*)s->pred)[1] = spanM;
        }
        __syncthreads();
        int fits = s->info[0], sA = s->info[1], sB = s->info[2];
        int tl0 = s->info[3], tm0 = s->info[4];
        int spanL = ((int*)s->pred)[0], spanM = ((int*)s->pred)[1];

        // ---- stage atoms (tid<128: one atom each) ----
        if (tid < 2 * TS) {
            int side = tid >> 6, idx = tid & (TS - 1);
            int a = (side ? m0 : l0) + idx;
            int v = s->atokp1[a];
            int tok = v ? v - 1 : 0;
            float oh = v ? s->tmk[tok] : 0.0f;
            float mk = Mb[a];
            s->ax[tid] = make_float4(Xb[a * 3], Xb[a * 3 + 1], Xb[a * 3 + 2], mk);
            s->ag[tid] = make_float4(Gb[a * 3], Gb[a * 3 + 1], Gb[a * 3 + 2], s->nuc[tok] * oh);
            s->af[tid] = make_float2(s->isl[tok] * oh, s->poly[tok] * oh);
            int base = side ? tm0 : tl0;
            int span = side ? spanM : spanL;
            s->rel[tid] = fits ? min(max(tok - base, 0), span - 1) : tok;
        }
        const float* tbg = tb + (size_t)b * NTOK * NTOK;
        if (fits) {
            int cntA = spanL * sA;
            for (int i = tid; i < cntA; i += 256) {
                int r = i / sA, cc = i - r * sA;
                if (cc < spanM) s->tbA[i] = tbg[(tl0 + r) * NTOK + tm0 + cc];
            }
            int cntB = spanM * sB;
            for (int i = tid; i < cntB; i += 256) {
                int r = i / sB, cc = i - r * sB;
                if (cc < spanL) s->tbB[i] = tbg[(tm0 + r) * NTOK + tl0 + cc];
            }
        }
        __syncthreads();

        // ---- per-thread l regs: 4 l-atoms, 4 m's per group (16 groups) ----
        int lt = tid & 15, mg = tid >> 4;
        float4 lx4[4], lg4[4]; float2 lf2[4]; int lrel[4], gl[4];
        #pragma unroll
        for (int k = 0; k < 4; k++) {
            int li = lt + 16 * k;
            lx4[k] = s->ax[li]; lg4[k] = s->ag[li]; lf2[k] = s->af[li];
            lrel[k] = s->rel[li]; gl[k] = l0 + li;
        }
        float bnum = 0.f, bden = 0.f, ce = 0.f, cs = 0.f;

        auto run = [&](auto ldA, auto ldB) {
            int mstart = mg * 4;
            if (diag) {
                #pragma unroll 2
                for (int j = 0; j < 4; j++) {
                    int m = mstart + j;
                    float4 mx4 = s->ax[TS + m], mg4 = s->ag[TS + m];
                    float2 mf = s->af[TS + m];
                    int mr = s->rel[TS + m];
                    int gm = m0 + m;
                    #pragma unroll
                    for (int k = 0; k < 4; k++) {
                        float dx0 = lx4[k].x - mx4.x, dx1 = lx4[k].y - mx4.y, dx2 = lx4[k].z - mx4.z;
                        float dg0 = lg4[k].x - mg4.x, dg1 = lg4[k].y - mg4.y, dg2 = lg4[k].z - mg4.z;
                        float dxv = fsqrt_(fmaf(dx2, dx2, fmaf(dx1, dx1, fmaf(dx0, dx0, 1e-12f))));
                        float dgv = fsqrt_(fmaf(dg2, dg2, fmaf(dg1, dg1, fmaf(dg0, dg0, 1e-12f))));
                        float diff = dxv - dgv;
                        float tbv = ldA(lrel[k], mr);
                        float pm = lx4[k].w * mx4.w;
                        float bmv = tbv * lf2[k].x * mf.y * pm;
                        bden += bmv;
                        bnum = fmaf(diff * diff, bmv, bnum);
                        float es = lddt_es(fabsf(diff));
                        float nl = lg4[k].w;
                        float ccv = dgv < 30.0f ? (dgv < 15.0f ? 1.0f : nl) : 0.0f;
                        float pm2 = (gl[k] != gm) ? pm : 0.0f;
                        float cm2 = ccv * pm2;
                        cs += cm2;
                        ce = fmaf(cm2 * 0.25f, es, ce);
                    }
                }
            } else {
                #pragma unroll 2
                for (int j = 0; j < 4; j++) {
                    int m = mstart + j;
                    float4 mx4 = s->ax[TS + m], mg4 = s->ag[TS + m];
                    float2 mf = s->af[TS + m];
                    int mr = s->rel[TS + m];
                    #pragma unroll
                    for (int k = 0; k < 4; k++) {
                        float dx0 = lx4[k].x - mx4.x, dx1 = lx4[k].y - mx4.y, dx2 = lx4[k].z - mx4.z;
                        float dg0 = lg4[k].x - mg4.x, dg1 = lg4[k].y - mg4.y, dg2 = lg4[k].z - mg4.z;
                        float dxv = fsqrt_(fmaf(dx2, dx2, fmaf(dx1, dx1, fmaf(dx0, dx0, 1e-12f))));
                        float dgv = fsqrt_(fmaf(dg2, dg2, fmaf(dg1, dg1, fmaf(dg0, dg0, 1e-12f))));
                        float diff = dxv - dgv;
                        float pm = lx4[k].w * mx4.w;
                        float tb1 = ldA(lrel[k], mr);
                        float tb2 = ldB(mr, lrel[k]);
                        float bsum = (tb1 * lf2[k].x * mf.y + tb2 * mf.x * lf2[k].y) * pm;
                        bden += bsum;
                        bnum = fmaf(diff * diff, bsum, bnum);
                        float es = lddt_es(fabsf(diff));
                        float sn = lg4[k].w + mg4.w;
                        float ccv = (dgv < 30.0f ? sn : 0.0f) + (dgv < 15.0f ? (2.0f - sn) : 0.0f);
                        float cm2 = ccv * pm;
                        cs += cm2;
                        ce = fmaf(cm2 * 0.25f, es, ce);
                    }
                }
            }
        };
        if (fits) run([&](int r, int c) -> float { return s->tbA[r * sA + c]; },
                      [&](int r, int c) -> float { return s->tbB[r * sB + c]; });
        else      run([&](int r, int c) -> float { return tbg[r * NTOK + c]; },
                      [&](int r, int c) -> float { return tbg[r * NTOK + c]; });

        // ---- block reduction -> one float4 store ----
        float vals[4] = {bnum, bden, ce, cs};
        #pragma unroll
        for (int q = 0; q < 4; q++) {
            float v = fred64(vals[q]);
            if (lane == 0) s->pred[wvi][q] = v;
        }
        __syncthreads();
        if (tid == 0) {
            float4 o;
            o.x = s->pred[0][0] + s->pred[1][0] + s->pred[2][0] + s->pred[3][0];
            o.y = s->pred[0][1] + s->pred[1][1] + s->pred[2][1] + s->pred[3][1];
            o.z = s->pred[0][2] + s->pred[1][2] + s->pred[2][2] + s->pred[3][2];
            o.w = s->pred[0][3] + s->pred[1][3] + s->pred[2][3] + s->pred[3][3];
            partials4[(size_t)b * NTRI + tri] = o;
        }
    } else {
        // ================= align path (one block per batch) =================
        AlignSh* s = (AlignSh*)smem;
        int b = id;

        {
            int n = npt[b * NTOK + tid];
            int v = n;
            #pragma unroll
            for (int o = 1; o < 64; o <<= 1) {
                int u = __shfl_up(v, o, 64);
                if (lane >= o) v += u;
            }
            if (lane == 63) s->wsum[wvi] = v;
            float pd = is_d[b * NTOK + tid], pr = is_r[b * NTOK + tid];
            float pl = is_l[b * NTOK + tid];
            float wtv = (1.0f + 5.0f * pd + 5.0f * pr + 10.0f * pl) * tok_mask[b * NTOK + tid];
            __syncthreads();
            int pref = 0;
            for (int w = 0; w < wvi; w++) pref += s->wsum[w];
            int total_ = s->wsum[0] + s->wsum[1] + s->wsum[2] + s->wsum[3];
            int cum = v + pref;
            int end = min(cum, NATOM), start = min(cum - n, NATOM);
            for (int i = start; i < end; i++) s->aw[i] = wtv;
            for (int i = total_ + tid; i < NATOM; i += 256) s->aw[i] = 0.0f;   // tail only
        }
        __syncthreads();

        const float* X = x + (size_t)b * NATOM * 3;
        const float* G = gt + (size_t)b * NATOM * 3;
        const float* M = gmask + (size_t)b * NATOM;

        double p[17];
        #pragma unroll
        for (int q = 0; q < 17; q++) p[q] = 0.0;
        for (int a = tid; a < NATOM; a += 256) {
            double m = M[a], wm = (double)s->aw[a] * m;
            double x0 = X[a * 3], x1 = X[a * 3 + 1], x2 = X[a * 3 + 2];
            double g0 = G[a * 3], g1 = G[a * 3 + 1], g2 = G[a * 3 + 2];
            p[0] += m; p[1] += wm;
            p[2] += wm * x0; p[3] += wm * x1; p[4] += wm * x2;
            p[5] += wm * g0; p[6] += wm * g1; p[7] += wm * g2;
            p[8]  += wm * x0 * g0; p[9]  += wm * x0 * g1; p[10] += wm * x0 * g2;
            p[11] += wm * x1 * g0; p[12] += wm * x1 * g1; p[13] += wm * x1 * g2;
            p[14] += wm * x2 * g0; p[15] += wm * x2 * g1; p[16] += wm * x2 * g2;
        }
        #pragma unroll
        for (int q = 0; q < 17; q++) {
            double v = wred64(p[q]);
            if (lane == 0) s->dred[wvi][q] = v;
        }
        __syncthreads();
        if (tid == 0) {
            double sh[17];
            for (int q = 0; q < 17; q++)
                sh[q] = s->dred[0][q] + s->dred[1][q] + s->dred[2][q] + s->dred[3][q];
            double ms;
            kabsch_from_sums(sh, s->Rf, s->muf, &ms);
            s->msum = ms;
        }
        __syncthreads();

        float R00 = s->Rf[0], R01 = s->Rf[1], R02 = s->Rf[2];
        float R10 = s->Rf[3], R11 = s->Rf[4], R12 = s->Rf[5];
        float R20 = s->Rf[6], R21 = s->Rf[7], R22 = s->Rf[8];
        float mux0 = s->muf[0], mux1 = s->muf[1], mux2 = s->muf[2];
        float mug0 = s->muf[3], mug1 = s->muf[4], mug2 = s->muf[5];
        double part = 0.0;
        for (int a = tid; a < NATOM; a += 256) {
            float w = s->aw[a], m = M[a];
            float gc0 = G[a * 3] - mug0, gc1 = G[a * 3 + 1] - mug1, gc2 = G[a * 3 + 2] - mug2;
            float al0 = fmaf(R00, gc0, fmaf(R01, gc1, fmaf(R02, gc2, mux0)));
            float al1 = fmaf(R10, gc0, fmaf(R11, gc1, fmaf(R12, gc2, mux1)));
            float al2 = fmaf(R20, gc0, fmaf(R21, gc1, fmaf(R22, gc2, mux2)));
            float r0 = X[a * 3] - al0, r1 = X[a * 3 + 1] - al1, r2 = X[a * 3 + 2] - al2;
            part += (double)(w * m * (r0 * r0 + r1 * r1 + r2 * r2));
        }
        {
            double v = wred64(part);
            if (lane == 0) s->mred[wvi] = v;
        }
        __syncthreads();
        if (tid == 0)
            lmse[b] = (float)((s->mred[0] + s->mred[1] + s->mred[2] + s->mred[3]) / (3.0 * s->msum));
    }
}

// ============ final: reduce pair partials + combine ============
__global__ __launch_bounds__(256) void final_kernel(
    const float4* __restrict__ partials4, const float* __restrict__ lmse,
    const float* __restrict__ t, float* __restrict__ out)
{
    int tid = threadIdx.x, lane = tid & 63, wv = tid >> 6;
    double pr[2][4] = {{0, 0, 0, 0}, {0, 0, 0, 0}};
    #pragma unroll
    for (int b = 0; b < BATCH; b++)
        for (int sI = tid; sI < NTRI; sI += 256) {
            float4 v = partials4[(size_t)b * NTRI + sI];
            pr[b][0] += v.x; pr[b][1] += v.y; pr[b][2] += v.z; pr[b][3] += v.w;
        }
    __shared__ double sred[4][8];
    #pragma unroll
    for (int b = 0; b < BATCH; b++)
        #pragma unroll
        for (int q = 0; q < 4; q++) {
            double v = wred64(pr[b][q]);
            if (lane == 0) sred[wv][b * 4 + q] = v;
        }
    __syncthreads();
    if (tid == 0) {
        double tot = 0.0;
        for (int b = 0; b < BATCH; b++) {
            double bn = 0, bd = 0, ce = 0, cs = 0;
            for (int w = 0; w < 4; w++) {
                bn += sred[w][b * 4 + 0]; bd += sred[w][b * 4 + 1];
                ce += sred[w][b * 4 + 2]; cs += sred[w][b * 4 + 3];
            }
            double l_bond = bn / bd;
            double l_lddt = 1.0 - ce / cs;
            double tt = t[b];
            double w_t = (tt * tt + 256.0) / ((tt + 16.0) * (tt + 16.0));
            tot += w_t * ((double)lmse[b] + l_bond) + l_lddt;
        }
        out[0] = (float)(tot / (double)BATCH);
    }
}

extern "C" void kernel_launch(void* const* d_in, const int* in_sizes, int n_in,
                              void* d_out, int out_size, void* d_ws, size_t ws_size,
                              hipStream_t stream) {
    const float* x     = (const float*)d_in[0];
    const float* gt    = (const float*)d_in[1];
    const float* gmask = (const float*)d_in[2];
    const float* is_p  = (const float*)d_in[3];
    const float* is_d  = (const float*)d_in[4];
    const float* is_r  = (const float*)d_in[5];
    const float* is_l  = (const float*)d_in[6];
    const float* tb    = (const float*)d_in[7];
    const float* tm    = (const float*)d_in[8];
    const int*   npt   = (const int*)d_in[9];
    const float* t     = (const float*)d_in[10];
    float* out = (float*)d_out;

    float4* partials4 = (float4*)d_ws;                                    // [BATCH][NTRI]
    float*  lmse      = (float*)((char*)d_ws + (size_t)BATCH * NTRI * sizeof(float4));

    pair_align_kernel<<<BATCH + BATCH * NTRI, 256, 0, stream>>>(
        x, gt, gmask, tb, is_p, is_d, is_r, is_l, tm, npt, partials4, lmse);
    final_kernel<<<1, 256, 0, stream>>>(partials4, lmse, t, out);
}